// Round 9
// baseline (186.401 us; speedup 1.0000x reference)
//
#include <hip/hip_runtime.h>
#include <math.h>

// MFA Woodbury log-likelihood:
//   per_comp[k,n] = c0_k + x.w_k - 0.5*x^2.iD_k + 0.5*||G_k^T x - h_k||^2
//   out[n] = logsumexp_k per_comp[k,n]
// As = sqrt(iD).*A (bf16); L = As^T As + I; rank-4 blocked Gauss elimination on
// S=[L|I] -> [U | L_unit^{-1}]; Winv = diag(rsqrt(diag U)) Xu; Gt fused (MFMA).
// main computes BOTH x@Gt^T (+SSQ epilogue) and r12 = xaug@Waug^T (bx=0 blocks).
// 4 dispatches: prep, percomp, main, lse.

#define KC 128
#define DF 512
#define LF 64
#define NN 4096

typedef __attribute__((ext_vector_type(8))) short short8;
typedef __attribute__((ext_vector_type(4))) float f32x4;

static __device__ __forceinline__ unsigned short bfr(float f) {
  union { float f; unsigned u; } v; v.f = f;
  return (unsigned short)((v.u + 0x7FFFu + ((v.u >> 16) & 1u)) >> 16);
}
static __device__ __forceinline__ float b2f(unsigned short u) {
  union { unsigned u; float f; } v; v.u = ((unsigned)u) << 16; return v.f;
}
static __device__ __forceinline__ void ldst16(void* lds, const void* g) {
  __builtin_amdgcn_global_load_lds((const __attribute__((address_space(1))) void*)g,
                                   (__attribute__((address_space(3))) void*)lds,
                                   16, 0, 0);
}

// ============ PREP: x -> xaug=[x|x^2] bf16 ; A -> As (d-major) + Ast (i-major) ============
__global__ __launch_bounds__(256) void mfa_prep(const float* __restrict__ x,
                                                const float* __restrict__ A,
                                                const float* __restrict__ Dp,
                                                unsigned short* __restrict__ xaug,
                                                unsigned short* __restrict__ As,
                                                unsigned short* __restrict__ Ast) {
  int b = blockIdx.x, tid = threadIdx.x;
  if (b < 1024) {
    int k = b >> 3, dc = b & 7;
    __shared__ float siDs[64];
    __shared__ unsigned short Tr[64][72];
    if (tid < 64) siDs[tid] = 1.0f / Dp[k * DF + dc * 64 + tid];
    __syncthreads();
#pragma unroll
    for (int q = 0; q < 4; ++q) {
      int f = q * 256 + tid;
      int dd = f >> 4, i4 = (f & 15) * 4;
      float4 v = *reinterpret_cast<const float4*>(&A[((size_t)(k * DF + dc * 64 + dd)) * LF + i4]);
      float s = siDs[dd];
      ushort4 u;
      u.x = bfr(v.x * s); u.y = bfr(v.y * s); u.z = bfr(v.z * s); u.w = bfr(v.w * s);
      *reinterpret_cast<ushort4*>(&As[((size_t)(k * DF + dc * 64 + dd)) * LF + i4]) = u;
      *reinterpret_cast<ushort4*>(&Tr[dd][i4]) = u;
    }
    __syncthreads();
    int i = tid >> 2, ds0 = (tid & 3) * 16;
    unsigned short t16[16];
#pragma unroll
    for (int e = 0; e < 16; ++e) t16[e] = Tr[ds0 + e][i];
    uint4 v0, v1;
    v0.x = (unsigned)t16[0] | ((unsigned)t16[1] << 16);
    v0.y = (unsigned)t16[2] | ((unsigned)t16[3] << 16);
    v0.z = (unsigned)t16[4] | ((unsigned)t16[5] << 16);
    v0.w = (unsigned)t16[6] | ((unsigned)t16[7] << 16);
    v1.x = (unsigned)t16[8] | ((unsigned)t16[9] << 16);
    v1.y = (unsigned)t16[10] | ((unsigned)t16[11] << 16);
    v1.z = (unsigned)t16[12] | ((unsigned)t16[13] << 16);
    v1.w = (unsigned)t16[14] | ((unsigned)t16[15] << 16);
    size_t ro = ((size_t)(k * LF + i)) * DF + dc * 64 + ds0;
    *reinterpret_cast<uint4*>(&Ast[ro]) = v0;
    *reinterpret_cast<uint4*>(&Ast[ro + 8]) = v1;
  } else {
    int f = (b - 1024) * 256 + tid;      // float4 index over NN*DF/4
    float4 v = reinterpret_cast<const float4*>(x)[f];
    int n = f >> 7, c4 = (f & 127) << 2;
    ushort4 a, s;
    a.x = bfr(v.x); a.y = bfr(v.y); a.z = bfr(v.z); a.w = bfr(v.w);
    s.x = bfr(v.x * v.x); s.y = bfr(v.y * v.y); s.z = bfr(v.z * v.z); s.w = bfr(v.w * v.w);
    *reinterpret_cast<ushort4*>(&xaug[(size_t)n * 1024 + c4]) = a;
    *reinterpret_cast<ushort4*>(&xaug[(size_t)n * 1024 + 512 + c4]) = s;
  }
}

// ============ PERCOMP: per k — stats, batched-prefetch syrk+m2, rank-4 elim, h, c0, Gt ============
__global__ __launch_bounds__(256) void mfa_percomp(const float* __restrict__ MU,
                                                   const float* __restrict__ Dp,
                                                   const float* __restrict__ PI,
                                                   const unsigned short* __restrict__ Ast,
                                                   const unsigned short* __restrict__ As,
                                                   unsigned short* __restrict__ Waug,
                                                   unsigned short* __restrict__ Gt,
                                                   float* __restrict__ hws,
                                                   float* __restrict__ c0g) {
  int k = blockIdx.x, tid = threadIdx.x, lane = tid & 63, w = tid >> 6;
  __shared__ float S[64 * 132];            // [L|Xu] stride 132; syrk Tile + gt bufs alias this
  __shared__ unsigned short Wbs[64 * 64];
  __shared__ float smuS[DF];
  __shared__ float m2part[256];
  __shared__ float m2S[64];
  __shared__ float invd_s[64];
  __shared__ float redq[80];
  __shared__ float c0a_s;
  unsigned short* Tile = reinterpret_cast<unsigned short*>(S);  // 32 KB (4 kt-tiles)

  // ---- phase B: stats, smu, Waug ----
  {
    float slog = 0.f, smu2 = 0.f;
#pragma unroll
    for (int p = 0; p < 2; ++p) {
      int d = p * 256 + tid;
      float Dv = Dp[k * DF + d];
      float id = 1.f / (Dv * Dv);
      float mu = MU[k * DF + d];
      float wv = id * mu;
      smuS[d] = mu / Dv;
      Waug[(size_t)k * 1024 + d] = bfr(wv);
      Waug[(size_t)k * 1024 + 512 + d] = bfr(-0.5f * id);
      slog += logf(id);
      smu2 += wv * mu;
    }
#pragma unroll
    for (int m = 1; m < 64; m <<= 1) {
      slog += __shfl_xor(slog, m, 64);
      smu2 += __shfl_xor(smu2, m, 64);
    }
    if (lane == 0) { redq[w] = slog; redq[8 + w] = smu2; }
  }
  __syncthreads();
  if (tid == 0) {
    float sl = 0.f, sm = 0.f;
    for (int q = 0; q < 4; ++q) { sl += redq[q]; sm += redq[8 + q]; }
    c0a_s = PI[k] - 0.5f * (DF * 1.8378770664093453f + sm - sl);
  }

  // ---- phase A: L = Ast Ast^T (MFMA, batched 4-tile prefetch) + fused m2 ----
  f32x4 accL[4];
  f32x4 zero = {0.f, 0.f, 0.f, 0.f};
#pragma unroll
  for (int nj = 0; nj < 4; ++nj) accL[nj] = zero;
  int lr = lane >> 3, lc = lane & 7;
  int gcs = (lc ^ lr) * 8;
  float m2acc = 0.f;
  int mi_i = tid & 63, mi_g = tid >> 6;
  for (int half = 0; half < 2; ++half) {
    __syncthreads();   // previous round's reads done before restaging
#pragma unroll
    for (int kt2 = 0; kt2 < 4; ++kt2) {
      int kt = half * 4 + kt2;
#pragma unroll
      for (int it = 0; it < 2; ++it) {
        int row = w * 8 + it * 32 + lr;
        ldst16(&Tile[(kt2 * 64 + w * 8 + it * 32) * 64],
               Ast + ((size_t)(k * LF + row)) * DF + kt * 64 + gcs);
      }
    }
    __syncthreads();
#pragma unroll
    for (int kt2 = 0; kt2 < 4; ++kt2) {
#pragma unroll
      for (int kk = 0; kk < 2; ++kk) {
        int sw = ((kk * 4 + (lane >> 4)) ^ (lane & 7)) * 8;
        short8 av = *reinterpret_cast<const short8*>(&Tile[(kt2 * 64 + w * 16 + (lane & 15)) * 64 + sw]);
#pragma unroll
        for (int nj = 0; nj < 4; ++nj) {
          short8 bv = *reinterpret_cast<const short8*>(&Tile[(kt2 * 64 + nj * 16 + (lane & 15)) * 64 + sw]);
          accL[nj] = __builtin_amdgcn_mfma_f32_16x16x32_bf16(av, bv, accL[nj], 0, 0, 0);
        }
      }
#pragma unroll
      for (int c2 = 0; c2 < 2; ++c2) {
        int g = mi_g * 2 + c2;
        int slot = g ^ (mi_i & 7);
        const unsigned* cp = reinterpret_cast<const unsigned*>(&Tile[(kt2 * 64 + mi_i) * 64 + slot * 8]);
#pragma unroll
        for (int u2 = 0; u2 < 4; ++u2) {
          unsigned uu = cp[u2];
          int d0 = (half * 4 + kt2) * 64 + g * 8 + u2 * 2;
          m2acc += b2f((unsigned short)(uu & 0xFFFF)) * smuS[d0];
          m2acc += b2f((unsigned short)(uu >> 16)) * smuS[d0 + 1];
        }
      }
    }
  }
  __syncthreads();   // all Tile reads done; S (aliasing Tile) may be written
  // ---- init Xu = I and write L (+I) into S ----
  for (int idx = tid; idx < 4096; idx += 256) {
    int r = idx >> 6, c = idx & 63;
    S[r * 132 + 64 + c] = (r == c) ? 1.f : 0.f;
  }
#pragma unroll
  for (int nj = 0; nj < 4; ++nj)
#pragma unroll
    for (int reg = 0; reg < 4; ++reg) {
      int m = w * 16 + (lane >> 4) * 4 + reg;
      int n = nj * 16 + (lane & 15);
      S[m * 132 + n] = accL[nj][reg] + (m == n ? 1.f : 0.f);
    }
  m2part[tid] = m2acc;
  __syncthreads();
  if (tid < 64) m2S[tid] = m2part[tid] + m2part[tid + 64] + m2part[tid + 128] + m2part[tid + 192];

  // ---- phase D: rank-4 blocked Gauss elimination on S=[L|I] ----
  {
    int rg = tid >> 4, cg = tid & 15;
    for (int Jo = 0; Jo < 16; ++Jo) {
      int J = Jo * 4;
      __syncthreads();
      f32x4 B0 = *reinterpret_cast<f32x4*>(&S[(J + 0) * 132 + J]);
      f32x4 B1 = *reinterpret_cast<f32x4*>(&S[(J + 1) * 132 + J]);
      f32x4 B2 = *reinterpret_cast<f32x4*>(&S[(J + 2) * 132 + J]);
      f32x4 B3 = *reinterpret_cast<f32x4*>(&S[(J + 3) * 132 + J]);
      int cc = J + 4 + cg * 4;
      f32x4 S0 = *reinterpret_cast<f32x4*>(&S[(J + 0) * 132 + cc]);
      f32x4 S1 = *reinterpret_cast<f32x4*>(&S[(J + 1) * 132 + cc]);
      f32x4 S2 = *reinterpret_cast<f32x4*>(&S[(J + 2) * 132 + cc]);
      f32x4 S3 = *reinterpret_cast<f32x4*>(&S[(J + 3) * 132 + cc]);
      f32x4 V[4], TGT[4];
#pragma unroll
      for (int a = 0; a < 4; ++a) {
        int r = J + rg + 16 * a;
        if (r < 64) {
          V[a] = *reinterpret_cast<f32x4*>(&S[r * 132 + J]);
          TGT[a] = *reinterpret_cast<f32x4*>(&S[r * 132 + cc]);
        }
      }
      __syncthreads();
      float p0 = 1.0f / B0[0];
      float m10 = B1[0] * p0;  B1 -= m10 * B0;
      float m20 = B2[0] * p0;  B2 -= m20 * B0;
      float m30 = B3[0] * p0;  B3 -= m30 * B0;
      float p1 = 1.0f / B1[1];
      float m21 = B2[1] * p1;  B2 -= m21 * B1;
      float m31 = B3[1] * p1;  B3 -= m31 * B1;
      float p2 = 1.0f / B2[2];
      float m32 = B3[2] * p2;  B3 -= m32 * B2;
      float p3 = 1.0f / B3[3];
      float T1_0 = -m10;
      float T2_1 = -m21, T2_0 = -m20 - m21 * T1_0;
      float T3_2 = -m32, T3_1 = -m31 - m32 * T2_1, T3_0 = -m30 - m31 * T1_0 - m32 * T2_0;
      if (cg == 0 && rg < 4) {
        f32x4 bw = (rg == 0) ? B0 : (rg == 1) ? B1 : (rg == 2) ? B2 : B3;
        *reinterpret_cast<f32x4*>(&S[(J + rg) * 132 + J]) = bw;
      }
#pragma unroll
      for (int a = 0; a < 4; ++a) {
        int r = J + rg + 16 * a;
        if (r < 64) {
          f32x4 v = V[a];
          float n0 = v[0] * p0;
          float t1 = v[1] - n0 * B0[1];
          float n1 = t1 * p1;
          float t2 = v[2] - n0 * B0[2] - n1 * B1[2];
          float n2 = t2 * p2;
          float t3 = v[3] - n0 * B0[3] - n1 * B1[3] - n2 * B2[3];
          float n3 = t3 * p3;
          int pi = r - J;
          if (pi < 1) n0 = 0.f;
          if (pi < 2) n1 = 0.f;
          if (pi < 3) n2 = 0.f;
          if (pi < 4) n3 = 0.f;
          float cA = n0 + n1 * T1_0 + n2 * T2_0 + n3 * T3_0;
          float cB = n1 + n2 * T2_1 + n3 * T3_1;
          float cC = n2 + n3 * T3_2;
          float cD = n3;
          f32x4 res = TGT[a] - cA * S0 - cB * S1 - cC * S2 - cD * S3;
          *reinterpret_cast<f32x4*>(&S[r * 132 + cc]) = res;
        }
      }
    }
  }
  __syncthreads();
  // ---- diag, logdet, invd ----
  if (tid < 64) {
    float dg2 = S[tid * 132 + tid];
    invd_s[tid] = rsqrtf(dg2);
    redq[tid] = logf(dg2);
  }
  __syncthreads();
  if (tid == 0) {
    float s = 0.f;
    for (int q = 0; q < 64; ++q) s += redq[q];
    c0g[k] = c0a_s - 0.5f * s;
  }
  // ---- h = diag(invd) * (Xu m2) ----
  if (tid < 64) {
    float hsum = 0.f;
#pragma unroll
    for (int j2 = 0; j2 < 64; ++j2) hsum += S[tid * 132 + 64 + j2] * m2S[j2];
    hws[k * 64 + tid] = hsum * invd_s[tid];
  }
  // ---- phase H: build Wbs (bf16, swizzled chunk layout) from Xu ----
  {
    int l = tid >> 2;
#pragma unroll
    for (int q = 0; q < 2; ++q) {
      int sc = (tid & 3) * 2 + q;
      int gch = sc ^ (l & 7);
      float il = invd_s[l];
      unsigned short t8[8];
#pragma unroll
      for (int e = 0; e < 8; ++e) t8[e] = bfr(il * S[l * 132 + 64 + gch * 8 + e]);
      uint4 val;
      val.x = (unsigned)t8[0] | ((unsigned)t8[1] << 16);
      val.y = (unsigned)t8[2] | ((unsigned)t8[3] << 16);
      val.z = (unsigned)t8[4] | ((unsigned)t8[5] << 16);
      val.w = (unsigned)t8[6] | ((unsigned)t8[7] << 16);
      *reinterpret_cast<uint4*>(&Wbs[l * 64 + sc * 8]) = val;
    }
  }
  __syncthreads();   // S dead below: aliased by DsA/CoutA
  // ---- phase I: Gt = siD .* (Wb @ As^T), 4 d-quarters, MFMA ----
  unsigned short* DsA = reinterpret_cast<unsigned short*>(S);          // 128*64 ush
  unsigned short* CoutA = reinterpret_cast<unsigned short*>(S) + 8192; // 64*132 ush
  f32x4 zero2 = {0.f, 0.f, 0.f, 0.f};
  for (int dq = 0; dq < 4; ++dq) {
#pragma unroll
    for (int it = 0; it < 4; ++it) {
      int row = w * 8 + it * 32 + lr;
      ldst16(&DsA[(w * 8 + it * 32) * 64], As + ((size_t)(k * DF + dq * 128 + row)) * LF + gcs);
    }
    __syncthreads();
    f32x4 gacc[4][2];
#pragma unroll
    for (int mi = 0; mi < 4; ++mi)
#pragma unroll
      for (int nj = 0; nj < 2; ++nj) gacc[mi][nj] = zero2;
#pragma unroll
    for (int kk = 0; kk < 2; ++kk) {
      int sw = ((kk * 4 + (lane >> 4)) ^ (lane & 7)) * 8;
      short8 av[4], bv[2];
#pragma unroll
      for (int mi = 0; mi < 4; ++mi)
        av[mi] = *reinterpret_cast<const short8*>(&Wbs[(mi * 16 + (lane & 15)) * 64 + sw]);
#pragma unroll
      for (int nj = 0; nj < 2; ++nj)
        bv[nj] = *reinterpret_cast<const short8*>(&DsA[(w * 32 + nj * 16 + (lane & 15)) * 64 + sw]);
#pragma unroll
      for (int mi = 0; mi < 4; ++mi)
#pragma unroll
        for (int nj = 0; nj < 2; ++nj)
          gacc[mi][nj] = __builtin_amdgcn_mfma_f32_16x16x32_bf16(av[mi], bv[nj], gacc[mi][nj], 0, 0, 0);
    }
    float siD[2];
#pragma unroll
    for (int nj = 0; nj < 2; ++nj)
      siD[nj] = 1.0f / Dp[k * DF + dq * 128 + w * 32 + nj * 16 + (lane & 15)];
#pragma unroll
    for (int mi = 0; mi < 4; ++mi)
#pragma unroll
      for (int nj = 0; nj < 2; ++nj) {
        int dl = w * 32 + nj * 16 + (lane & 15);
#pragma unroll
        for (int reg = 0; reg < 4; ++reg) {
          int l = mi * 16 + (lane >> 4) * 4 + reg;
          CoutA[l * 132 + dl] = bfr(gacc[mi][nj][reg] * siD[nj]);
        }
      }
    __syncthreads();
    {
      int l = tid >> 2, seg = (tid & 3) * 32;
      uint4* dst = reinterpret_cast<uint4*>(&Gt[((size_t)(k * LF + l)) * DF + dq * 128 + seg]);
#pragma unroll
      for (int u = 0; u < 4; ++u) {
        unsigned short t8[8];
#pragma unroll
        for (int e = 0; e < 8; ++e) t8[e] = CoutA[l * 132 + seg + u * 8 + e];
        uint4 val;
        val.x = (unsigned)t8[0] | ((unsigned)t8[1] << 16);
        val.y = (unsigned)t8[2] | ((unsigned)t8[3] << 16);
        val.z = (unsigned)t8[4] | ((unsigned)t8[5] << 16);
        val.w = (unsigned)t8[6] | ((unsigned)t8[7] << 16);
        dst[u] = val;
      }
    }
    __syncthreads();
  }
}

// ============ MAIN: comp blocks (bx>=1): x@Gt^T + 0.5||u-h||^2 + c0 -> s2b
//              heavy blocks (bx==0): r12 = xaug @ Waug^T (K=1024) ============
__global__ __launch_bounds__(256) void mfa_main(const unsigned short* __restrict__ xaug,
                                                const unsigned short* __restrict__ Gt,
                                                const unsigned short* __restrict__ Waug,
                                                const float* __restrict__ hws,
                                                const float* __restrict__ c0g,
                                                float* __restrict__ r12,
                                                float* __restrict__ s2b) {
  int bx = blockIdx.x, by = blockIdx.y;
  int tid = threadIdx.x, lane = tid & 63, w = tid >> 6, wx = w & 1, wy = w >> 1;
  __shared__ unsigned short As[128 * 64];
  __shared__ unsigned short Bs[128 * 64];
  f32x4 acc[4][4];
  f32x4 zero = {0.f, 0.f, 0.f, 0.f};
#pragma unroll
  for (int mi = 0; mi < 4; ++mi)
#pragma unroll
    for (int nj = 0; nj < 4; ++nj) acc[mi][nj] = zero;
  bool heavy = (bx == 0);
  int nkt = heavy ? 16 : 8;
  int nbase = by * 128;
  const unsigned short* xg = xaug + (size_t)nbase * 1024;
  const unsigned short* gg;
  size_t bstride;
  if (heavy) { gg = Waug; bstride = 1024; }
  else       { gg = Gt + (size_t)((bx - 1) * 128) * DF; bstride = DF; }
  int lr = lane >> 3, lc = lane & 7;
  int gcs = (lc ^ lr) * 8;
  for (int kt = 0; kt < nkt; ++kt) {
#pragma unroll
    for (int it = 0; it < 4; ++it) {
      int row = w * 8 + it * 32 + lr;
      ldst16(&As[(w * 8 + it * 32) * 64], xg + (size_t)row * 1024 + kt * 64 + gcs);
      ldst16(&Bs[(w * 8 + it * 32) * 64], gg + (size_t)row * bstride + kt * 64 + gcs);
    }
    __syncthreads();
#pragma unroll
    for (int kk = 0; kk < 2; ++kk) {
      int sw = ((kk * 4 + (lane >> 4)) ^ (lane & 7)) * 8;
      short8 av[4], bv[4];
#pragma unroll
      for (int mi = 0; mi < 4; ++mi)
        av[mi] = *reinterpret_cast<const short8*>(&As[(wy * 64 + mi * 16 + (lane & 15)) * 64 + sw]);
#pragma unroll
      for (int nj = 0; nj < 4; ++nj)
        bv[nj] = *reinterpret_cast<const short8*>(&Bs[(wx * 64 + nj * 16 + (lane & 15)) * 64 + sw]);
#pragma unroll
      for (int mi = 0; mi < 4; ++mi)
#pragma unroll
        for (int nj = 0; nj < 4; ++nj)
          acc[mi][nj] = __builtin_amdgcn_mfma_f32_16x16x32_bf16(av[mi], bv[nj], acc[mi][nj], 0, 0, 0);
    }
    __syncthreads();
  }
  if (heavy) {
    // write r12[comp][n] = acc directly
#pragma unroll
    for (int mi = 0; mi < 4; ++mi)
#pragma unroll
      for (int nj = 0; nj < 4; ++nj) {
        int ccol = wx * 64 + nj * 16 + (lane & 15);
        int nrow = nbase + wy * 64 + mi * 16 + (lane >> 4) * 4;
        float4 o;
        o.x = acc[mi][nj][0]; o.y = acc[mi][nj][1]; o.z = acc[mi][nj][2]; o.w = acc[mi][nj][3];
        *reinterpret_cast<float4*>(&r12[(size_t)ccol * NN + nrow]) = o;
      }
  } else {
    int comp = (bx - 1) * 2 + wx;
    float hv[4];
#pragma unroll
    for (int nj = 0; nj < 4; ++nj) hv[nj] = hws[comp * 64 + nj * 16 + (lane & 15)];
    float cc = c0g[comp];
    int rbase = nbase + wy * 64;
#pragma unroll
    for (int mi = 0; mi < 4; ++mi) {
      f32x4 sv;
#pragma unroll
      for (int reg = 0; reg < 4; ++reg) {
        float s = 0.f;
#pragma unroll
        for (int nj = 0; nj < 4; ++nj) {
          float dlt = acc[mi][nj][reg] - hv[nj];
          s += dlt * dlt;
        }
        s += __shfl_xor(s, 1, 64);
        s += __shfl_xor(s, 2, 64);
        s += __shfl_xor(s, 4, 64);
        s += __shfl_xor(s, 8, 64);
        sv[reg] = s;
      }
      if ((lane & 15) == 0) {
        int nr = rbase + mi * 16 + (lane >> 4) * 4;
        size_t idx = (size_t)comp * NN + nr;
        float4 o;
        o.x = 0.5f * sv[0] + cc;
        o.y = 0.5f * sv[1] + cc;
        o.z = 0.5f * sv[2] + cc;
        o.w = 0.5f * sv[3] + cc;
        *reinterpret_cast<float4*>(&s2b[idx]) = o;
      }
    }
  }
}

// ============ LSE over K ============
__global__ __launch_bounds__(64) void mfa_lse(const float* __restrict__ s2b,
                                              const float* __restrict__ r12,
                                              float* __restrict__ out) {
  int n = blockIdx.x * 64 + threadIdx.x;
  float m = -3.0e38f, s = 0.f;
#pragma unroll 8
  for (int k = 0; k < KC; ++k) {
    float t = s2b[(size_t)k * NN + n] + r12[(size_t)k * NN + n];
    float nm = fmaxf(m, t);
    s = s * expf(m - nm) + expf(t - nm);
    m = nm;
  }
  out[n] = m + logf(s);
}

extern "C" void kernel_launch(void* const* d_in, const int* in_sizes, int n_in,
                              void* d_out, int out_size, void* d_ws, size_t ws_size,
                              hipStream_t stream) {
  const float* x  = (const float*)d_in[0];
  const float* MU = (const float*)d_in[1];
  const float* A  = (const float*)d_in[2];
  const float* Dp = (const float*)d_in[3];
  const float* PI = (const float*)d_in[4];
  float* out = (float*)d_out;

  char* base = (char*)d_ws;
  size_t off = 0;
  auto alloc = [&](size_t bytes) -> void* {
    void* p = base + off;
    off += (bytes + 255) & ~(size_t)255;
    return p;
  };
  unsigned short* xaug = (unsigned short*)alloc((size_t)NN * 1024 * 2);    // 16 MB
  unsigned short* As   = (unsigned short*)alloc((size_t)KC * DF * LF * 2); // 8 MB
  unsigned short* Ast  = (unsigned short*)alloc((size_t)KC * LF * DF * 2); // 8 MB
  unsigned short* Waug = (unsigned short*)alloc((size_t)KC * 1024 * 2);    // 256 KB
  unsigned short* Gt   = (unsigned short*)alloc((size_t)KC * LF * DF * 2); // 8 MB
  float* hws           = (float*)alloc((size_t)KC * 64 * 4);
  float* c0g           = (float*)alloc((size_t)KC * 4);
  float* r12           = (float*)alloc((size_t)KC * NN * 4);               // 2 MB
  float* s2b           = (float*)alloc((size_t)KC * NN * 4);               // 2 MB

  mfa_prep<<<3072, 256, 0, stream>>>(x, A, Dp, xaug, As, Ast);
  mfa_percomp<<<KC, 256, 0, stream>>>(MU, Dp, PI, Ast, As, Waug, Gt, hws, c0g);
  mfa_main<<<dim3(65, NN / 128), 256, 0, stream>>>(xaug, Gt, Waug, hws, c0g, r12, s2b);
  mfa_lse<<<NN / 64, 64, 0, stream>>>(s2b, r12, out);
}

// Round 10
// 179.510 us; speedup vs baseline: 1.0384x; 1.0384x over previous
//
#include <hip/hip_runtime.h>
#include <math.h>

// MFA Woodbury log-likelihood:
//   per_comp[k,n] = c0_k + x.w_k - 0.5*x^2.iD_k + 0.5*||G_k^T x - h_k||^2
//   out[n] = logsumexp_k per_comp[k,n]
// As = sqrt(iD).*A (bf16); L = As^T As + I; rank-4 blocked Gauss elimination on
// S=[L|I] -> [U | L_unit^{-1}]; Winv = diag(rsqrt(diag U)) Xu; Gt fused (MFMA).
// main: grid (72,32) — 72 ≡ 0 mod 8 keeps comp-tile→XCD mapping row-stable
// (L2 keeps each Gt tile resident); bx<64 comp, bx==64+(by&7) heavy r12, rest exit.
// 4 dispatches: prep, percomp, main, lse.

#define KC 128
#define DF 512
#define LF 64
#define NN 4096

typedef __attribute__((ext_vector_type(8))) short short8;
typedef __attribute__((ext_vector_type(4))) float f32x4;

static __device__ __forceinline__ unsigned short bfr(float f) {
  union { float f; unsigned u; } v; v.f = f;
  return (unsigned short)((v.u + 0x7FFFu + ((v.u >> 16) & 1u)) >> 16);
}
static __device__ __forceinline__ float b2f(unsigned short u) {
  union { unsigned u; float f; } v; v.u = ((unsigned)u) << 16; return v.f;
}
static __device__ __forceinline__ void ldst16(void* lds, const void* g) {
  __builtin_amdgcn_global_load_lds((const __attribute__((address_space(1))) void*)g,
                                   (__attribute__((address_space(3))) void*)lds,
                                   16, 0, 0);
}

// ============ PREP: x -> xaug=[x|x^2] bf16 ; A -> As (d-major) + Ast (i-major) ============
__global__ __launch_bounds__(256) void mfa_prep(const float* __restrict__ x,
                                                const float* __restrict__ A,
                                                const float* __restrict__ Dp,
                                                unsigned short* __restrict__ xaug,
                                                unsigned short* __restrict__ As,
                                                unsigned short* __restrict__ Ast) {
  int b = blockIdx.x, tid = threadIdx.x;
  if (b < 1024) {
    int k = b >> 3, dc = b & 7;
    __shared__ float siDs[64];
    __shared__ unsigned short Tr[64][72];
    if (tid < 64) siDs[tid] = 1.0f / Dp[k * DF + dc * 64 + tid];
    __syncthreads();
#pragma unroll
    for (int q = 0; q < 4; ++q) {
      int f = q * 256 + tid;
      int dd = f >> 4, i4 = (f & 15) * 4;
      float4 v = *reinterpret_cast<const float4*>(&A[((size_t)(k * DF + dc * 64 + dd)) * LF + i4]);
      float s = siDs[dd];
      ushort4 u;
      u.x = bfr(v.x * s); u.y = bfr(v.y * s); u.z = bfr(v.z * s); u.w = bfr(v.w * s);
      *reinterpret_cast<ushort4*>(&As[((size_t)(k * DF + dc * 64 + dd)) * LF + i4]) = u;
      *reinterpret_cast<ushort4*>(&Tr[dd][i4]) = u;
    }
    __syncthreads();
    int i = tid >> 2, ds0 = (tid & 3) * 16;
    unsigned short t16[16];
#pragma unroll
    for (int e = 0; e < 16; ++e) t16[e] = Tr[ds0 + e][i];
    uint4 v0, v1;
    v0.x = (unsigned)t16[0] | ((unsigned)t16[1] << 16);
    v0.y = (unsigned)t16[2] | ((unsigned)t16[3] << 16);
    v0.z = (unsigned)t16[4] | ((unsigned)t16[5] << 16);
    v0.w = (unsigned)t16[6] | ((unsigned)t16[7] << 16);
    v1.x = (unsigned)t16[8] | ((unsigned)t16[9] << 16);
    v1.y = (unsigned)t16[10] | ((unsigned)t16[11] << 16);
    v1.z = (unsigned)t16[12] | ((unsigned)t16[13] << 16);
    v1.w = (unsigned)t16[14] | ((unsigned)t16[15] << 16);
    size_t ro = ((size_t)(k * LF + i)) * DF + dc * 64 + ds0;
    *reinterpret_cast<uint4*>(&Ast[ro]) = v0;
    *reinterpret_cast<uint4*>(&Ast[ro + 8]) = v1;
  } else {
    int f = (b - 1024) * 256 + tid;      // float4 index over NN*DF/4
    float4 v = reinterpret_cast<const float4*>(x)[f];
    int n = f >> 7, c4 = (f & 127) << 2;
    ushort4 a, s;
    a.x = bfr(v.x); a.y = bfr(v.y); a.z = bfr(v.z); a.w = bfr(v.w);
    s.x = bfr(v.x * v.x); s.y = bfr(v.y * v.y); s.z = bfr(v.z * v.z); s.w = bfr(v.w * v.w);
    *reinterpret_cast<ushort4*>(&xaug[(size_t)n * 1024 + c4]) = a;
    *reinterpret_cast<ushort4*>(&xaug[(size_t)n * 1024 + 512 + c4]) = s;
  }
}

// ============ PERCOMP: per k — stats, batched-prefetch syrk+m2, rank-4 elim, h, c0, Gt ============
__global__ __launch_bounds__(256) void mfa_percomp(const float* __restrict__ MU,
                                                   const float* __restrict__ Dp,
                                                   const float* __restrict__ PI,
                                                   const unsigned short* __restrict__ Ast,
                                                   const unsigned short* __restrict__ As,
                                                   unsigned short* __restrict__ Waug,
                                                   unsigned short* __restrict__ Gt,
                                                   float* __restrict__ hws,
                                                   float* __restrict__ c0g) {
  int k = blockIdx.x, tid = threadIdx.x, lane = tid & 63, w = tid >> 6;
  __shared__ float S[64 * 132];            // [L|Xu] stride 132; syrk Tile + gt bufs alias this
  __shared__ unsigned short Wbs[64 * 64];
  __shared__ float smuS[DF];
  __shared__ float m2part[256];
  __shared__ float m2S[64];
  __shared__ float invd_s[64];
  __shared__ float redq[80];
  __shared__ float c0a_s;
  unsigned short* Tile = reinterpret_cast<unsigned short*>(S);  // 32 KB (4 kt-tiles)

  // ---- phase B: stats, smu, Waug ----
  {
    float slog = 0.f, smu2 = 0.f;
#pragma unroll
    for (int p = 0; p < 2; ++p) {
      int d = p * 256 + tid;
      float Dv = Dp[k * DF + d];
      float id = 1.f / (Dv * Dv);
      float mu = MU[k * DF + d];
      float wv = id * mu;
      smuS[d] = mu / Dv;
      Waug[(size_t)k * 1024 + d] = bfr(wv);
      Waug[(size_t)k * 1024 + 512 + d] = bfr(-0.5f * id);
      slog += logf(id);
      smu2 += wv * mu;
    }
#pragma unroll
    for (int m = 1; m < 64; m <<= 1) {
      slog += __shfl_xor(slog, m, 64);
      smu2 += __shfl_xor(smu2, m, 64);
    }
    if (lane == 0) { redq[w] = slog; redq[8 + w] = smu2; }
  }
  __syncthreads();
  if (tid == 0) {
    float sl = 0.f, sm = 0.f;
    for (int q = 0; q < 4; ++q) { sl += redq[q]; sm += redq[8 + q]; }
    c0a_s = PI[k] - 0.5f * (DF * 1.8378770664093453f + sm - sl);
  }

  // ---- phase A: L = Ast Ast^T (MFMA, batched 4-tile prefetch) + fused m2 ----
  f32x4 accL[4];
  f32x4 zero = {0.f, 0.f, 0.f, 0.f};
#pragma unroll
  for (int nj = 0; nj < 4; ++nj) accL[nj] = zero;
  int lr = lane >> 3, lc = lane & 7;
  int gcs = (lc ^ lr) * 8;
  float m2acc = 0.f;
  int mi_i = tid & 63, mi_g = tid >> 6;
  for (int half = 0; half < 2; ++half) {
    __syncthreads();   // previous round's reads done before restaging
#pragma unroll
    for (int kt2 = 0; kt2 < 4; ++kt2) {
      int kt = half * 4 + kt2;
#pragma unroll
      for (int it = 0; it < 2; ++it) {
        int row = w * 8 + it * 32 + lr;
        ldst16(&Tile[(kt2 * 64 + w * 8 + it * 32) * 64],
               Ast + ((size_t)(k * LF + row)) * DF + kt * 64 + gcs);
      }
    }
    __syncthreads();
#pragma unroll
    for (int kt2 = 0; kt2 < 4; ++kt2) {
#pragma unroll
      for (int kk = 0; kk < 2; ++kk) {
        int sw = ((kk * 4 + (lane >> 4)) ^ (lane & 7)) * 8;
        short8 av = *reinterpret_cast<const short8*>(&Tile[(kt2 * 64 + w * 16 + (lane & 15)) * 64 + sw]);
#pragma unroll
        for (int nj = 0; nj < 4; ++nj) {
          short8 bv = *reinterpret_cast<const short8*>(&Tile[(kt2 * 64 + nj * 16 + (lane & 15)) * 64 + sw]);
          accL[nj] = __builtin_amdgcn_mfma_f32_16x16x32_bf16(av, bv, accL[nj], 0, 0, 0);
        }
      }
#pragma unroll
      for (int c2 = 0; c2 < 2; ++c2) {
        int g = mi_g * 2 + c2;
        int slot = g ^ (mi_i & 7);
        const unsigned* cp = reinterpret_cast<const unsigned*>(&Tile[(kt2 * 64 + mi_i) * 64 + slot * 8]);
#pragma unroll
        for (int u2 = 0; u2 < 4; ++u2) {
          unsigned uu = cp[u2];
          int d0 = (half * 4 + kt2) * 64 + g * 8 + u2 * 2;
          m2acc += b2f((unsigned short)(uu & 0xFFFF)) * smuS[d0];
          m2acc += b2f((unsigned short)(uu >> 16)) * smuS[d0 + 1];
        }
      }
    }
  }
  __syncthreads();   // all Tile reads done; S (aliasing Tile) may be written
  // ---- init Xu = I and write L (+I) into S ----
  for (int idx = tid; idx < 4096; idx += 256) {
    int r = idx >> 6, c = idx & 63;
    S[r * 132 + 64 + c] = (r == c) ? 1.f : 0.f;
  }
#pragma unroll
  for (int nj = 0; nj < 4; ++nj)
#pragma unroll
    for (int reg = 0; reg < 4; ++reg) {
      int m = w * 16 + (lane >> 4) * 4 + reg;
      int n = nj * 16 + (lane & 15);
      S[m * 132 + n] = accL[nj][reg] + (m == n ? 1.f : 0.f);
    }
  m2part[tid] = m2acc;
  __syncthreads();
  if (tid < 64) m2S[tid] = m2part[tid] + m2part[tid + 64] + m2part[tid + 128] + m2part[tid + 192];

  // ---- phase D: rank-4 blocked Gauss elimination on S=[L|I] ----
  {
    int rg = tid >> 4, cg = tid & 15;
    for (int Jo = 0; Jo < 16; ++Jo) {
      int J = Jo * 4;
      __syncthreads();
      f32x4 B0 = *reinterpret_cast<f32x4*>(&S[(J + 0) * 132 + J]);
      f32x4 B1 = *reinterpret_cast<f32x4*>(&S[(J + 1) * 132 + J]);
      f32x4 B2 = *reinterpret_cast<f32x4*>(&S[(J + 2) * 132 + J]);
      f32x4 B3 = *reinterpret_cast<f32x4*>(&S[(J + 3) * 132 + J]);
      int cc = J + 4 + cg * 4;
      f32x4 S0 = *reinterpret_cast<f32x4*>(&S[(J + 0) * 132 + cc]);
      f32x4 S1 = *reinterpret_cast<f32x4*>(&S[(J + 1) * 132 + cc]);
      f32x4 S2 = *reinterpret_cast<f32x4*>(&S[(J + 2) * 132 + cc]);
      f32x4 S3 = *reinterpret_cast<f32x4*>(&S[(J + 3) * 132 + cc]);
      f32x4 V[4], TGT[4];
#pragma unroll
      for (int a = 0; a < 4; ++a) {
        int r = J + rg + 16 * a;
        if (r < 64) {
          V[a] = *reinterpret_cast<f32x4*>(&S[r * 132 + J]);
          TGT[a] = *reinterpret_cast<f32x4*>(&S[r * 132 + cc]);
        }
      }
      __syncthreads();
      float p0 = 1.0f / B0[0];
      float m10 = B1[0] * p0;  B1 -= m10 * B0;
      float m20 = B2[0] * p0;  B2 -= m20 * B0;
      float m30 = B3[0] * p0;  B3 -= m30 * B0;
      float p1 = 1.0f / B1[1];
      float m21 = B2[1] * p1;  B2 -= m21 * B1;
      float m31 = B3[1] * p1;  B3 -= m31 * B1;
      float p2 = 1.0f / B2[2];
      float m32 = B3[2] * p2;  B3 -= m32 * B2;
      float p3 = 1.0f / B3[3];
      float T1_0 = -m10;
      float T2_1 = -m21, T2_0 = -m20 - m21 * T1_0;
      float T3_2 = -m32, T3_1 = -m31 - m32 * T2_1, T3_0 = -m30 - m31 * T1_0 - m32 * T2_0;
      if (cg == 0 && rg < 4) {
        f32x4 bw = (rg == 0) ? B0 : (rg == 1) ? B1 : (rg == 2) ? B2 : B3;
        *reinterpret_cast<f32x4*>(&S[(J + rg) * 132 + J]) = bw;
      }
#pragma unroll
      for (int a = 0; a < 4; ++a) {
        int r = J + rg + 16 * a;
        if (r < 64) {
          f32x4 v = V[a];
          float n0 = v[0] * p0;
          float t1 = v[1] - n0 * B0[1];
          float n1 = t1 * p1;
          float t2 = v[2] - n0 * B0[2] - n1 * B1[2];
          float n2 = t2 * p2;
          float t3 = v[3] - n0 * B0[3] - n1 * B1[3] - n2 * B2[3];
          float n3 = t3 * p3;
          int pi = r - J;
          if (pi < 1) n0 = 0.f;
          if (pi < 2) n1 = 0.f;
          if (pi < 3) n2 = 0.f;
          if (pi < 4) n3 = 0.f;
          float cA = n0 + n1 * T1_0 + n2 * T2_0 + n3 * T3_0;
          float cB = n1 + n2 * T2_1 + n3 * T3_1;
          float cC = n2 + n3 * T3_2;
          float cD = n3;
          f32x4 res = TGT[a] - cA * S0 - cB * S1 - cC * S2 - cD * S3;
          *reinterpret_cast<f32x4*>(&S[r * 132 + cc]) = res;
        }
      }
    }
  }
  __syncthreads();
  // ---- diag, logdet, invd ----
  if (tid < 64) {
    float dg2 = S[tid * 132 + tid];
    invd_s[tid] = rsqrtf(dg2);
    redq[tid] = logf(dg2);
  }
  __syncthreads();
  if (tid == 0) {
    float s = 0.f;
    for (int q = 0; q < 64; ++q) s += redq[q];
    c0g[k] = c0a_s - 0.5f * s;
  }
  // ---- h = diag(invd) * (Xu m2) ----
  if (tid < 64) {
    float hsum = 0.f;
#pragma unroll
    for (int j2 = 0; j2 < 64; ++j2) hsum += S[tid * 132 + 64 + j2] * m2S[j2];
    hws[k * 64 + tid] = hsum * invd_s[tid];
  }
  // ---- phase H: build Wbs (bf16, swizzled chunk layout) from Xu ----
  {
    int l = tid >> 2;
#pragma unroll
    for (int q = 0; q < 2; ++q) {
      int sc = (tid & 3) * 2 + q;
      int gch = sc ^ (l & 7);
      float il = invd_s[l];
      unsigned short t8[8];
#pragma unroll
      for (int e = 0; e < 8; ++e) t8[e] = bfr(il * S[l * 132 + 64 + gch * 8 + e]);
      uint4 val;
      val.x = (unsigned)t8[0] | ((unsigned)t8[1] << 16);
      val.y = (unsigned)t8[2] | ((unsigned)t8[3] << 16);
      val.z = (unsigned)t8[4] | ((unsigned)t8[5] << 16);
      val.w = (unsigned)t8[6] | ((unsigned)t8[7] << 16);
      *reinterpret_cast<uint4*>(&Wbs[l * 64 + sc * 8]) = val;
    }
  }
  __syncthreads();   // S dead below: aliased by DsA/CoutA
  // ---- phase I: Gt = siD .* (Wb @ As^T), 4 d-quarters, MFMA ----
  unsigned short* DsA = reinterpret_cast<unsigned short*>(S);          // 128*64 ush
  unsigned short* CoutA = reinterpret_cast<unsigned short*>(S) + 8192; // 64*132 ush
  f32x4 zero2 = {0.f, 0.f, 0.f, 0.f};
  for (int dq = 0; dq < 4; ++dq) {
#pragma unroll
    for (int it = 0; it < 4; ++it) {
      int row = w * 8 + it * 32 + lr;
      ldst16(&DsA[(w * 8 + it * 32) * 64], As + ((size_t)(k * DF + dq * 128 + row)) * LF + gcs);
    }
    __syncthreads();
    f32x4 gacc[4][2];
#pragma unroll
    for (int mi = 0; mi < 4; ++mi)
#pragma unroll
      for (int nj = 0; nj < 2; ++nj) gacc[mi][nj] = zero2;
#pragma unroll
    for (int kk = 0; kk < 2; ++kk) {
      int sw = ((kk * 4 + (lane >> 4)) ^ (lane & 7)) * 8;
      short8 av[4], bv[2];
#pragma unroll
      for (int mi = 0; mi < 4; ++mi)
        av[mi] = *reinterpret_cast<const short8*>(&Wbs[(mi * 16 + (lane & 15)) * 64 + sw]);
#pragma unroll
      for (int nj = 0; nj < 2; ++nj)
        bv[nj] = *reinterpret_cast<const short8*>(&DsA[(w * 32 + nj * 16 + (lane & 15)) * 64 + sw]);
#pragma unroll
      for (int mi = 0; mi < 4; ++mi)
#pragma unroll
        for (int nj = 0; nj < 2; ++nj)
          gacc[mi][nj] = __builtin_amdgcn_mfma_f32_16x16x32_bf16(av[mi], bv[nj], gacc[mi][nj], 0, 0, 0);
    }
    float siD[2];
#pragma unroll
    for (int nj = 0; nj < 2; ++nj)
      siD[nj] = 1.0f / Dp[k * DF + dq * 128 + w * 32 + nj * 16 + (lane & 15)];
#pragma unroll
    for (int mi = 0; mi < 4; ++mi)
#pragma unroll
      for (int nj = 0; nj < 2; ++nj) {
        int dl = w * 32 + nj * 16 + (lane & 15);
#pragma unroll
        for (int reg = 0; reg < 4; ++reg) {
          int l = mi * 16 + (lane >> 4) * 4 + reg;
          CoutA[l * 132 + dl] = bfr(gacc[mi][nj][reg] * siD[nj]);
        }
      }
    __syncthreads();
    {
      int l = tid >> 2, seg = (tid & 3) * 32;
      uint4* dst = reinterpret_cast<uint4*>(&Gt[((size_t)(k * LF + l)) * DF + dq * 128 + seg]);
#pragma unroll
      for (int u = 0; u < 4; ++u) {
        unsigned short t8[8];
#pragma unroll
        for (int e = 0; e < 8; ++e) t8[e] = CoutA[l * 132 + seg + u * 8 + e];
        uint4 val;
        val.x = (unsigned)t8[0] | ((unsigned)t8[1] << 16);
        val.y = (unsigned)t8[2] | ((unsigned)t8[3] << 16);
        val.z = (unsigned)t8[4] | ((unsigned)t8[5] << 16);
        val.w = (unsigned)t8[6] | ((unsigned)t8[7] << 16);
        dst[u] = val;
      }
    }
    __syncthreads();
  }
}

// ============ MAIN: grid (72, 32); bx<64 comp tile; bx==64+(by&7) heavy r12; else exit ============
__global__ __launch_bounds__(256) void mfa_main(const unsigned short* __restrict__ xaug,
                                                const unsigned short* __restrict__ Gt,
                                                const unsigned short* __restrict__ Waug,
                                                const float* __restrict__ hws,
                                                const float* __restrict__ c0g,
                                                float* __restrict__ r12,
                                                float* __restrict__ s2b) {
  int bx = blockIdx.x, by = blockIdx.y;
  bool heavy = false;
  if (bx >= 64) {
    if (bx != 64 + (by & 7)) return;   // idle filler block (keeps grid.x % 8 == 0)
    heavy = true;
  }
  int tid = threadIdx.x, lane = tid & 63, w = tid >> 6, wx = w & 1, wy = w >> 1;
  __shared__ unsigned short As[128 * 64];
  __shared__ unsigned short Bs[128 * 64];
  f32x4 acc[4][4];
  f32x4 zero = {0.f, 0.f, 0.f, 0.f};
#pragma unroll
  for (int mi = 0; mi < 4; ++mi)
#pragma unroll
    for (int nj = 0; nj < 4; ++nj) acc[mi][nj] = zero;
  int nkt = heavy ? 16 : 8;
  int nbase = by * 128;
  const unsigned short* xg = xaug + (size_t)nbase * 1024;
  const unsigned short* gg;
  size_t bstride;
  if (heavy) { gg = Waug; bstride = 1024; }
  else       { gg = Gt + (size_t)(bx * 128) * DF; bstride = DF; }
  int lr = lane >> 3, lc = lane & 7;
  int gcs = (lc ^ lr) * 8;
  for (int kt = 0; kt < nkt; ++kt) {
#pragma unroll
    for (int it = 0; it < 4; ++it) {
      int row = w * 8 + it * 32 + lr;
      ldst16(&As[(w * 8 + it * 32) * 64], xg + (size_t)row * 1024 + kt * 64 + gcs);
      ldst16(&Bs[(w * 8 + it * 32) * 64], gg + (size_t)row * bstride + kt * 64 + gcs);
    }
    __syncthreads();
#pragma unroll
    for (int kk = 0; kk < 2; ++kk) {
      int sw = ((kk * 4 + (lane >> 4)) ^ (lane & 7)) * 8;
      short8 av[4], bv[4];
#pragma unroll
      for (int mi = 0; mi < 4; ++mi)
        av[mi] = *reinterpret_cast<const short8*>(&As[(wy * 64 + mi * 16 + (lane & 15)) * 64 + sw]);
#pragma unroll
      for (int nj = 0; nj < 4; ++nj)
        bv[nj] = *reinterpret_cast<const short8*>(&Bs[(wx * 64 + nj * 16 + (lane & 15)) * 64 + sw]);
#pragma unroll
      for (int mi = 0; mi < 4; ++mi)
#pragma unroll
        for (int nj = 0; nj < 4; ++nj)
          acc[mi][nj] = __builtin_amdgcn_mfma_f32_16x16x32_bf16(av[mi], bv[nj], acc[mi][nj], 0, 0, 0);
    }
    __syncthreads();
  }
  if (heavy) {
#pragma unroll
    for (int mi = 0; mi < 4; ++mi)
#pragma unroll
      for (int nj = 0; nj < 4; ++nj) {
        int ccol = wx * 64 + nj * 16 + (lane & 15);
        int nrow = nbase + wy * 64 + mi * 16 + (lane >> 4) * 4;
        float4 o;
        o.x = acc[mi][nj][0]; o.y = acc[mi][nj][1]; o.z = acc[mi][nj][2]; o.w = acc[mi][nj][3];
        *reinterpret_cast<float4*>(&r12[(size_t)ccol * NN + nrow]) = o;
      }
  } else {
    int comp = bx * 2 + wx;
    float hv[4];
#pragma unroll
    for (int nj = 0; nj < 4; ++nj) hv[nj] = hws[comp * 64 + nj * 16 + (lane & 15)];
    float cc = c0g[comp];
    int rbase = nbase + wy * 64;
#pragma unroll
    for (int mi = 0; mi < 4; ++mi) {
      f32x4 sv;
#pragma unroll
      for (int reg = 0; reg < 4; ++reg) {
        float s = 0.f;
#pragma unroll
        for (int nj = 0; nj < 4; ++nj) {
          float dlt = acc[mi][nj][reg] - hv[nj];
          s += dlt * dlt;
        }
        s += __shfl_xor(s, 1, 64);
        s += __shfl_xor(s, 2, 64);
        s += __shfl_xor(s, 4, 64);
        s += __shfl_xor(s, 8, 64);
        sv[reg] = s;
      }
      if ((lane & 15) == 0) {
        int nr = rbase + mi * 16 + (lane >> 4) * 4;
        size_t idx = (size_t)comp * NN + nr;
        float4 o;
        o.x = 0.5f * sv[0] + cc;
        o.y = 0.5f * sv[1] + cc;
        o.z = 0.5f * sv[2] + cc;
        o.w = 0.5f * sv[3] + cc;
        *reinterpret_cast<float4*>(&s2b[idx]) = o;
      }
    }
  }
}

// ============ LSE over K ============
__global__ __launch_bounds__(64) void mfa_lse(const float* __restrict__ s2b,
                                              const float* __restrict__ r12,
                                              float* __restrict__ out) {
  int n = blockIdx.x * 64 + threadIdx.x;
  float m = -3.0e38f, s = 0.f;
#pragma unroll 8
  for (int k = 0; k < KC; ++k) {
    float t = s2b[(size_t)k * NN + n] + r12[(size_t)k * NN + n];
    float nm = fmaxf(m, t);
    s = s * expf(m - nm) + expf(t - nm);
    m = nm;
  }
  out[n] = m + logf(s);
}

extern "C" void kernel_launch(void* const* d_in, const int* in_sizes, int n_in,
                              void* d_out, int out_size, void* d_ws, size_t ws_size,
                              hipStream_t stream) {
  const float* x  = (const float*)d_in[0];
  const float* MU = (const float*)d_in[1];
  const float* A  = (const float*)d_in[2];
  const float* Dp = (const float*)d_in[3];
  const float* PI = (const float*)d_in[4];
  float* out = (float*)d_out;

  char* base = (char*)d_ws;
  size_t off = 0;
  auto alloc = [&](size_t bytes) -> void* {
    void* p = base + off;
    off += (bytes + 255) & ~(size_t)255;
    return p;
  };
  unsigned short* xaug = (unsigned short*)alloc((size_t)NN * 1024 * 2);    // 16 MB
  unsigned short* As   = (unsigned short*)alloc((size_t)KC * DF * LF * 2); // 8 MB
  unsigned short* Ast  = (unsigned short*)alloc((size_t)KC * LF * DF * 2); // 8 MB
  unsigned short* Waug = (unsigned short*)alloc((size_t)KC * 1024 * 2);    // 256 KB
  unsigned short* Gt   = (unsigned short*)alloc((size_t)KC * LF * DF * 2); // 8 MB
  float* hws           = (float*)alloc((size_t)KC * 64 * 4);
  float* c0g           = (float*)alloc((size_t)KC * 4);
  float* r12           = (float*)alloc((size_t)KC * NN * 4);               // 2 MB
  float* s2b           = (float*)alloc((size_t)KC * NN * 4);               // 2 MB

  mfa_prep<<<3072, 256, 0, stream>>>(x, A, Dp, xaug, As, Ast);
  mfa_percomp<<<KC, 256, 0, stream>>>(MU, Dp, PI, Ast, As, Waug, Gt, hws, c0g);
  mfa_main<<<dim3(72, NN / 128), 256, 0, stream>>>(xaug, Gt, Waug, hws, c0g, r12, s2b);
  mfa_lse<<<NN / 64, 64, 0, stream>>>(s2b, r12, out);
}

// Round 11
// 175.872 us; speedup vs baseline: 1.0599x; 1.0207x over previous
//
#include <hip/hip_runtime.h>
#include <math.h>

// MFA Woodbury log-likelihood:
//   per_comp[k,n] = c0_k + x.w_k - 0.5*x^2.iD_k + 0.5*||G_k^T x - h_k||^2
//   out[n] = logsumexp_k per_comp[k,n]
// As = sqrt(iD).*A (bf16); L = As^T As + I; rank-4 blocked Gauss elimination on
// S=[L|I] -> [U | L_unit^{-1}]; Winv = diag(rsqrt(diag U)) Xu; Gt fused (MFMA).
// main: grid (72,32), 72 ≡ 0 mod 8 -> comp-tile→XCD map row-stable (Gt stays in
// its XCD's L2). bx<64 comp tile; bx-64 == (by&7) heavy r12 half 0 (x·w);
// bx-64 == (by&7)^1 heavy half 1 (-0.5x²·iD); rest exit. ALL blocks = 8 kt
// (equal duration -> no straggler tail).
// 4 dispatches: prep, percomp, main, lse.

#define KC 128
#define DF 512
#define LF 64
#define NN 4096

typedef __attribute__((ext_vector_type(8))) short short8;
typedef __attribute__((ext_vector_type(4))) float f32x4;

static __device__ __forceinline__ unsigned short bfr(float f) {
  union { float f; unsigned u; } v; v.f = f;
  return (unsigned short)((v.u + 0x7FFFu + ((v.u >> 16) & 1u)) >> 16);
}
static __device__ __forceinline__ float b2f(unsigned short u) {
  union { unsigned u; float f; } v; v.u = ((unsigned)u) << 16; return v.f;
}
static __device__ __forceinline__ void ldst16(void* lds, const void* g) {
  __builtin_amdgcn_global_load_lds((const __attribute__((address_space(1))) void*)g,
                                   (__attribute__((address_space(3))) void*)lds,
                                   16, 0, 0);
}

// ============ PREP: x -> xaug=[x|x^2] bf16 ; A -> As (d-major) + Ast (i-major) ============
__global__ __launch_bounds__(256) void mfa_prep(const float* __restrict__ x,
                                                const float* __restrict__ A,
                                                const float* __restrict__ Dp,
                                                unsigned short* __restrict__ xaug,
                                                unsigned short* __restrict__ As,
                                                unsigned short* __restrict__ Ast) {
  int b = blockIdx.x, tid = threadIdx.x;
  if (b < 1024) {
    int k = b >> 3, dc = b & 7;
    __shared__ float siDs[64];
    __shared__ unsigned short Tr[64][72];
    if (tid < 64) siDs[tid] = 1.0f / Dp[k * DF + dc * 64 + tid];
    __syncthreads();
#pragma unroll
    for (int q = 0; q < 4; ++q) {
      int f = q * 256 + tid;
      int dd = f >> 4, i4 = (f & 15) * 4;
      float4 v = *reinterpret_cast<const float4*>(&A[((size_t)(k * DF + dc * 64 + dd)) * LF + i4]);
      float s = siDs[dd];
      ushort4 u;
      u.x = bfr(v.x * s); u.y = bfr(v.y * s); u.z = bfr(v.z * s); u.w = bfr(v.w * s);
      *reinterpret_cast<ushort4*>(&As[((size_t)(k * DF + dc * 64 + dd)) * LF + i4]) = u;
      *reinterpret_cast<ushort4*>(&Tr[dd][i4]) = u;
    }
    __syncthreads();
    int i = tid >> 2, ds0 = (tid & 3) * 16;
    unsigned short t16[16];
#pragma unroll
    for (int e = 0; e < 16; ++e) t16[e] = Tr[ds0 + e][i];
    uint4 v0, v1;
    v0.x = (unsigned)t16[0] | ((unsigned)t16[1] << 16);
    v0.y = (unsigned)t16[2] | ((unsigned)t16[3] << 16);
    v0.z = (unsigned)t16[4] | ((unsigned)t16[5] << 16);
    v0.w = (unsigned)t16[6] | ((unsigned)t16[7] << 16);
    v1.x = (unsigned)t16[8] | ((unsigned)t16[9] << 16);
    v1.y = (unsigned)t16[10] | ((unsigned)t16[11] << 16);
    v1.z = (unsigned)t16[12] | ((unsigned)t16[13] << 16);
    v1.w = (unsigned)t16[14] | ((unsigned)t16[15] << 16);
    size_t ro = ((size_t)(k * LF + i)) * DF + dc * 64 + ds0;
    *reinterpret_cast<uint4*>(&Ast[ro]) = v0;
    *reinterpret_cast<uint4*>(&Ast[ro + 8]) = v1;
  } else {
    int f = (b - 1024) * 256 + tid;      // float4 index over NN*DF/4
    float4 v = reinterpret_cast<const float4*>(x)[f];
    int n = f >> 7, c4 = (f & 127) << 2;
    ushort4 a, s;
    a.x = bfr(v.x); a.y = bfr(v.y); a.z = bfr(v.z); a.w = bfr(v.w);
    s.x = bfr(v.x * v.x); s.y = bfr(v.y * v.y); s.z = bfr(v.z * v.z); s.w = bfr(v.w * v.w);
    *reinterpret_cast<ushort4*>(&xaug[(size_t)n * 1024 + c4]) = a;
    *reinterpret_cast<ushort4*>(&xaug[(size_t)n * 1024 + 512 + c4]) = s;
  }
}

// ============ PERCOMP: per k — stats, batched-prefetch syrk+m2, rank-4 elim, h, c0, Gt ============
__global__ __launch_bounds__(256) void mfa_percomp(const float* __restrict__ MU,
                                                   const float* __restrict__ Dp,
                                                   const float* __restrict__ PI,
                                                   const unsigned short* __restrict__ Ast,
                                                   const unsigned short* __restrict__ As,
                                                   unsigned short* __restrict__ Waug,
                                                   unsigned short* __restrict__ Gt,
                                                   float* __restrict__ hws,
                                                   float* __restrict__ c0g) {
  int k = blockIdx.x, tid = threadIdx.x, lane = tid & 63, w = tid >> 6;
  __shared__ float S[64 * 132];            // [L|Xu] stride 132; syrk Tile + gt bufs alias this
  __shared__ unsigned short Wbs[64 * 64];
  __shared__ float smuS[DF];
  __shared__ float m2part[256];
  __shared__ float m2S[64];
  __shared__ float invd_s[64];
  __shared__ float redq[80];
  __shared__ float c0a_s;
  unsigned short* Tile = reinterpret_cast<unsigned short*>(S);  // 32 KB (4 kt-tiles)

  // ---- phase B: stats, smu, Waug ----
  {
    float slog = 0.f, smu2 = 0.f;
#pragma unroll
    for (int p = 0; p < 2; ++p) {
      int d = p * 256 + tid;
      float Dv = Dp[k * DF + d];
      float id = 1.f / (Dv * Dv);
      float mu = MU[k * DF + d];
      float wv = id * mu;
      smuS[d] = mu / Dv;
      Waug[(size_t)k * 1024 + d] = bfr(wv);
      Waug[(size_t)k * 1024 + 512 + d] = bfr(-0.5f * id);
      slog += logf(id);
      smu2 += wv * mu;
    }
#pragma unroll
    for (int m = 1; m < 64; m <<= 1) {
      slog += __shfl_xor(slog, m, 64);
      smu2 += __shfl_xor(smu2, m, 64);
    }
    if (lane == 0) { redq[w] = slog; redq[8 + w] = smu2; }
  }
  __syncthreads();
  if (tid == 0) {
    float sl = 0.f, sm = 0.f;
    for (int q = 0; q < 4; ++q) { sl += redq[q]; sm += redq[8 + q]; }
    c0a_s = PI[k] - 0.5f * (DF * 1.8378770664093453f + sm - sl);
  }

  // ---- phase A: L = Ast Ast^T (MFMA, batched 4-tile prefetch) + fused m2 ----
  f32x4 accL[4];
  f32x4 zero = {0.f, 0.f, 0.f, 0.f};
#pragma unroll
  for (int nj = 0; nj < 4; ++nj) accL[nj] = zero;
  int lr = lane >> 3, lc = lane & 7;
  int gcs = (lc ^ lr) * 8;
  float m2acc = 0.f;
  int mi_i = tid & 63, mi_g = tid >> 6;
  for (int half = 0; half < 2; ++half) {
    __syncthreads();   // previous round's reads done before restaging
#pragma unroll
    for (int kt2 = 0; kt2 < 4; ++kt2) {
      int kt = half * 4 + kt2;
#pragma unroll
      for (int it = 0; it < 2; ++it) {
        int row = w * 8 + it * 32 + lr;
        ldst16(&Tile[(kt2 * 64 + w * 8 + it * 32) * 64],
               Ast + ((size_t)(k * LF + row)) * DF + kt * 64 + gcs);
      }
    }
    __syncthreads();
#pragma unroll
    for (int kt2 = 0; kt2 < 4; ++kt2) {
#pragma unroll
      for (int kk = 0; kk < 2; ++kk) {
        int sw = ((kk * 4 + (lane >> 4)) ^ (lane & 7)) * 8;
        short8 av = *reinterpret_cast<const short8*>(&Tile[(kt2 * 64 + w * 16 + (lane & 15)) * 64 + sw]);
#pragma unroll
        for (int nj = 0; nj < 4; ++nj) {
          short8 bv = *reinterpret_cast<const short8*>(&Tile[(kt2 * 64 + nj * 16 + (lane & 15)) * 64 + sw]);
          accL[nj] = __builtin_amdgcn_mfma_f32_16x16x32_bf16(av, bv, accL[nj], 0, 0, 0);
        }
      }
#pragma unroll
      for (int c2 = 0; c2 < 2; ++c2) {
        int g = mi_g * 2 + c2;
        int slot = g ^ (mi_i & 7);
        const unsigned* cp = reinterpret_cast<const unsigned*>(&Tile[(kt2 * 64 + mi_i) * 64 + slot * 8]);
#pragma unroll
        for (int u2 = 0; u2 < 4; ++u2) {
          unsigned uu = cp[u2];
          int d0 = (half * 4 + kt2) * 64 + g * 8 + u2 * 2;
          m2acc += b2f((unsigned short)(uu & 0xFFFF)) * smuS[d0];
          m2acc += b2f((unsigned short)(uu >> 16)) * smuS[d0 + 1];
        }
      }
    }
  }
  __syncthreads();   // all Tile reads done; S (aliasing Tile) may be written
  // ---- init Xu = I and write L (+I) into S ----
  for (int idx = tid; idx < 4096; idx += 256) {
    int r = idx >> 6, c = idx & 63;
    S[r * 132 + 64 + c] = (r == c) ? 1.f : 0.f;
  }
#pragma unroll
  for (int nj = 0; nj < 4; ++nj)
#pragma unroll
    for (int reg = 0; reg < 4; ++reg) {
      int m = w * 16 + (lane >> 4) * 4 + reg;
      int n = nj * 16 + (lane & 15);
      S[m * 132 + n] = accL[nj][reg] + (m == n ? 1.f : 0.f);
    }
  m2part[tid] = m2acc;
  __syncthreads();
  if (tid < 64) m2S[tid] = m2part[tid] + m2part[tid + 64] + m2part[tid + 128] + m2part[tid + 192];

  // ---- phase D: rank-4 blocked Gauss elimination on S=[L|I] ----
  {
    int rg = tid >> 4, cg = tid & 15;
    for (int Jo = 0; Jo < 16; ++Jo) {
      int J = Jo * 4;
      __syncthreads();
      f32x4 B0 = *reinterpret_cast<f32x4*>(&S[(J + 0) * 132 + J]);
      f32x4 B1 = *reinterpret_cast<f32x4*>(&S[(J + 1) * 132 + J]);
      f32x4 B2 = *reinterpret_cast<f32x4*>(&S[(J + 2) * 132 + J]);
      f32x4 B3 = *reinterpret_cast<f32x4*>(&S[(J + 3) * 132 + J]);
      int cc = J + 4 + cg * 4;
      f32x4 S0 = *reinterpret_cast<f32x4*>(&S[(J + 0) * 132 + cc]);
      f32x4 S1 = *reinterpret_cast<f32x4*>(&S[(J + 1) * 132 + cc]);
      f32x4 S2 = *reinterpret_cast<f32x4*>(&S[(J + 2) * 132 + cc]);
      f32x4 S3 = *reinterpret_cast<f32x4*>(&S[(J + 3) * 132 + cc]);
      f32x4 V[4], TGT[4];
#pragma unroll
      for (int a = 0; a < 4; ++a) {
        int r = J + rg + 16 * a;
        if (r < 64) {
          V[a] = *reinterpret_cast<f32x4*>(&S[r * 132 + J]);
          TGT[a] = *reinterpret_cast<f32x4*>(&S[r * 132 + cc]);
        }
      }
      __syncthreads();
      float p0 = 1.0f / B0[0];
      float m10 = B1[0] * p0;  B1 -= m10 * B0;
      float m20 = B2[0] * p0;  B2 -= m20 * B0;
      float m30 = B3[0] * p0;  B3 -= m30 * B0;
      float p1 = 1.0f / B1[1];
      float m21 = B2[1] * p1;  B2 -= m21 * B1;
      float m31 = B3[1] * p1;  B3 -= m31 * B1;
      float p2 = 1.0f / B2[2];
      float m32 = B3[2] * p2;  B3 -= m32 * B2;
      float p3 = 1.0f / B3[3];
      float T1_0 = -m10;
      float T2_1 = -m21, T2_0 = -m20 - m21 * T1_0;
      float T3_2 = -m32, T3_1 = -m31 - m32 * T2_1, T3_0 = -m30 - m31 * T1_0 - m32 * T2_0;
      if (cg == 0 && rg < 4) {
        f32x4 bw = (rg == 0) ? B0 : (rg == 1) ? B1 : (rg == 2) ? B2 : B3;
        *reinterpret_cast<f32x4*>(&S[(J + rg) * 132 + J]) = bw;
      }
#pragma unroll
      for (int a = 0; a < 4; ++a) {
        int r = J + rg + 16 * a;
        if (r < 64) {
          f32x4 v = V[a];
          float n0 = v[0] * p0;
          float t1 = v[1] - n0 * B0[1];
          float n1 = t1 * p1;
          float t2 = v[2] - n0 * B0[2] - n1 * B1[2];
          float n2 = t2 * p2;
          float t3 = v[3] - n0 * B0[3] - n1 * B1[3] - n2 * B2[3];
          float n3 = t3 * p3;
          int pi = r - J;
          if (pi < 1) n0 = 0.f;
          if (pi < 2) n1 = 0.f;
          if (pi < 3) n2 = 0.f;
          if (pi < 4) n3 = 0.f;
          float cA = n0 + n1 * T1_0 + n2 * T2_0 + n3 * T3_0;
          float cB = n1 + n2 * T2_1 + n3 * T3_1;
          float cC = n2 + n3 * T3_2;
          float cD = n3;
          f32x4 res = TGT[a] - cA * S0 - cB * S1 - cC * S2 - cD * S3;
          *reinterpret_cast<f32x4*>(&S[r * 132 + cc]) = res;
        }
      }
    }
  }
  __syncthreads();
  // ---- diag, logdet, invd ----
  if (tid < 64) {
    float dg2 = S[tid * 132 + tid];
    invd_s[tid] = rsqrtf(dg2);
    redq[tid] = logf(dg2);
  }
  __syncthreads();
  if (tid == 0) {
    float s = 0.f;
    for (int q = 0; q < 64; ++q) s += redq[q];
    c0g[k] = c0a_s - 0.5f * s;
  }
  // ---- h = diag(invd) * (Xu m2) ----
  if (tid < 64) {
    float hsum = 0.f;
#pragma unroll
    for (int j2 = 0; j2 < 64; ++j2) hsum += S[tid * 132 + 64 + j2] * m2S[j2];
    hws[k * 64 + tid] = hsum * invd_s[tid];
  }
  // ---- phase H: build Wbs (bf16, swizzled chunk layout) from Xu ----
  {
    int l = tid >> 2;
#pragma unroll
    for (int q = 0; q < 2; ++q) {
      int sc = (tid & 3) * 2 + q;
      int gch = sc ^ (l & 7);
      float il = invd_s[l];
      unsigned short t8[8];
#pragma unroll
      for (int e = 0; e < 8; ++e) t8[e] = bfr(il * S[l * 132 + 64 + gch * 8 + e]);
      uint4 val;
      val.x = (unsigned)t8[0] | ((unsigned)t8[1] << 16);
      val.y = (unsigned)t8[2] | ((unsigned)t8[3] << 16);
      val.z = (unsigned)t8[4] | ((unsigned)t8[5] << 16);
      val.w = (unsigned)t8[6] | ((unsigned)t8[7] << 16);
      *reinterpret_cast<uint4*>(&Wbs[l * 64 + sc * 8]) = val;
    }
  }
  __syncthreads();   // S dead below: aliased by DsA/CoutA
  // ---- phase I: Gt = siD .* (Wb @ As^T), 4 d-quarters, MFMA ----
  unsigned short* DsA = reinterpret_cast<unsigned short*>(S);          // 128*64 ush
  unsigned short* CoutA = reinterpret_cast<unsigned short*>(S) + 8192; // 64*132 ush
  f32x4 zero2 = {0.f, 0.f, 0.f, 0.f};
  for (int dq = 0; dq < 4; ++dq) {
#pragma unroll
    for (int it = 0; it < 4; ++it) {
      int row = w * 8 + it * 32 + lr;
      ldst16(&DsA[(w * 8 + it * 32) * 64], As + ((size_t)(k * DF + dq * 128 + row)) * LF + gcs);
    }
    __syncthreads();
    f32x4 gacc[4][2];
#pragma unroll
    for (int mi = 0; mi < 4; ++mi)
#pragma unroll
      for (int nj = 0; nj < 2; ++nj) gacc[mi][nj] = zero2;
#pragma unroll
    for (int kk = 0; kk < 2; ++kk) {
      int sw = ((kk * 4 + (lane >> 4)) ^ (lane & 7)) * 8;
      short8 av[4], bv[2];
#pragma unroll
      for (int mi = 0; mi < 4; ++mi)
        av[mi] = *reinterpret_cast<const short8*>(&Wbs[(mi * 16 + (lane & 15)) * 64 + sw]);
#pragma unroll
      for (int nj = 0; nj < 2; ++nj)
        bv[nj] = *reinterpret_cast<const short8*>(&DsA[(w * 32 + nj * 16 + (lane & 15)) * 64 + sw]);
#pragma unroll
      for (int mi = 0; mi < 4; ++mi)
#pragma unroll
        for (int nj = 0; nj < 2; ++nj)
          gacc[mi][nj] = __builtin_amdgcn_mfma_f32_16x16x32_bf16(av[mi], bv[nj], gacc[mi][nj], 0, 0, 0);
    }
    float siD[2];
#pragma unroll
    for (int nj = 0; nj < 2; ++nj)
      siD[nj] = 1.0f / Dp[k * DF + dq * 128 + w * 32 + nj * 16 + (lane & 15)];
#pragma unroll
    for (int mi = 0; mi < 4; ++mi)
#pragma unroll
      for (int nj = 0; nj < 2; ++nj) {
        int dl = w * 32 + nj * 16 + (lane & 15);
#pragma unroll
        for (int reg = 0; reg < 4; ++reg) {
          int l = mi * 16 + (lane >> 4) * 4 + reg;
          CoutA[l * 132 + dl] = bfr(gacc[mi][nj][reg] * siD[nj]);
        }
      }
    __syncthreads();
    {
      int l = tid >> 2, seg = (tid & 3) * 32;
      uint4* dst = reinterpret_cast<uint4*>(&Gt[((size_t)(k * LF + l)) * DF + dq * 128 + seg]);
#pragma unroll
      for (int u = 0; u < 4; ++u) {
        unsigned short t8[8];
#pragma unroll
        for (int e = 0; e < 8; ++e) t8[e] = CoutA[l * 132 + seg + u * 8 + e];
        uint4 val;
        val.x = (unsigned)t8[0] | ((unsigned)t8[1] << 16);
        val.y = (unsigned)t8[2] | ((unsigned)t8[3] << 16);
        val.z = (unsigned)t8[4] | ((unsigned)t8[5] << 16);
        val.w = (unsigned)t8[6] | ((unsigned)t8[7] << 16);
        dst[u] = val;
      }
    }
    __syncthreads();
  }
}

// ============ MAIN: grid (72, 32); bx<64 comp tile; bx-64==(by&7) r12 half 0;
//              bx-64==((by&7)^1) r12 half 1; else exit. All blocks = 8 kt. ============
__global__ __launch_bounds__(256) void mfa_main(const unsigned short* __restrict__ xaug,
                                                const unsigned short* __restrict__ Gt,
                                                const unsigned short* __restrict__ Waug,
                                                const float* __restrict__ hws,
                                                const float* __restrict__ c0g,
                                                float* __restrict__ r12a,
                                                float* __restrict__ r12b,
                                                float* __restrict__ s2b) {
  int bx = blockIdx.x, by = blockIdx.y;
  bool heavy = false;
  int half = 0;
  if (bx >= 64) {
    int slot = bx - 64, s0 = by & 7;
    if (slot == s0) { heavy = true; half = 0; }
    else if (slot == (s0 ^ 1)) { heavy = true; half = 1; }
    else return;                        // filler block (keeps grid.x % 8 == 0)
  }
  int tid = threadIdx.x, lane = tid & 63, w = tid >> 6, wx = w & 1, wy = w >> 1;
  __shared__ unsigned short As[128 * 64];
  __shared__ unsigned short Bs[128 * 64];
  f32x4 acc[4][4];
  f32x4 zero = {0.f, 0.f, 0.f, 0.f};
#pragma unroll
  for (int mi = 0; mi < 4; ++mi)
#pragma unroll
    for (int nj = 0; nj < 4; ++nj) acc[mi][nj] = zero;
  int nbase = by * 128;
  const unsigned short* xg = xaug + (size_t)nbase * 1024;
  const unsigned short* gg;
  size_t bstride;
  int kt0;
  if (heavy) { gg = Waug; bstride = 1024; kt0 = half * 8; }
  else       { gg = Gt + (size_t)(bx * 128) * DF; bstride = DF; kt0 = 0; }
  int lr = lane >> 3, lc = lane & 7;
  int gcs = (lc ^ lr) * 8;
  for (int kti = 0; kti < 8; ++kti) {
    int kt = kt0 + kti;
#pragma unroll
    for (int it = 0; it < 4; ++it) {
      int row = w * 8 + it * 32 + lr;
      ldst16(&As[(w * 8 + it * 32) * 64], xg + (size_t)row * 1024 + kt * 64 + gcs);
      ldst16(&Bs[(w * 8 + it * 32) * 64], gg + (size_t)row * bstride + kt * 64 + gcs);
    }
    __syncthreads();
#pragma unroll
    for (int kk = 0; kk < 2; ++kk) {
      int sw = ((kk * 4 + (lane >> 4)) ^ (lane & 7)) * 8;
      short8 av[4], bv[4];
#pragma unroll
      for (int mi = 0; mi < 4; ++mi)
        av[mi] = *reinterpret_cast<const short8*>(&As[(wy * 64 + mi * 16 + (lane & 15)) * 64 + sw]);
#pragma unroll
      for (int nj = 0; nj < 4; ++nj)
        bv[nj] = *reinterpret_cast<const short8*>(&Bs[(wx * 64 + nj * 16 + (lane & 15)) * 64 + sw]);
#pragma unroll
      for (int mi = 0; mi < 4; ++mi)
#pragma unroll
        for (int nj = 0; nj < 4; ++nj)
          acc[mi][nj] = __builtin_amdgcn_mfma_f32_16x16x32_bf16(av[mi], bv[nj], acc[mi][nj], 0, 0, 0);
    }
    __syncthreads();
  }
  if (heavy) {
    float* rout = half ? r12b : r12a;
#pragma unroll
    for (int mi = 0; mi < 4; ++mi)
#pragma unroll
      for (int nj = 0; nj < 4; ++nj) {
        int ccol = wx * 64 + nj * 16 + (lane & 15);
        int nrow = nbase + wy * 64 + mi * 16 + (lane >> 4) * 4;
        float4 o;
        o.x = acc[mi][nj][0]; o.y = acc[mi][nj][1]; o.z = acc[mi][nj][2]; o.w = acc[mi][nj][3];
        *reinterpret_cast<float4*>(&rout[(size_t)ccol * NN + nrow]) = o;
      }
  } else {
    int comp = bx * 2 + wx;
    float hv[4];
#pragma unroll
    for (int nj = 0; nj < 4; ++nj) hv[nj] = hws[comp * 64 + nj * 16 + (lane & 15)];
    float cc = c0g[comp];
    int rbase = nbase + wy * 64;
#pragma unroll
    for (int mi = 0; mi < 4; ++mi) {
      f32x4 sv;
#pragma unroll
      for (int reg = 0; reg < 4; ++reg) {
        float s = 0.f;
#pragma unroll
        for (int nj = 0; nj < 4; ++nj) {
          float dlt = acc[mi][nj][reg] - hv[nj];
          s += dlt * dlt;
        }
        s += __shfl_xor(s, 1, 64);
        s += __shfl_xor(s, 2, 64);
        s += __shfl_xor(s, 4, 64);
        s += __shfl_xor(s, 8, 64);
        sv[reg] = s;
      }
      if ((lane & 15) == 0) {
        int nr = rbase + mi * 16 + (lane >> 4) * 4;
        size_t idx = (size_t)comp * NN + nr;
        float4 o;
        o.x = 0.5f * sv[0] + cc;
        o.y = 0.5f * sv[1] + cc;
        o.z = 0.5f * sv[2] + cc;
        o.w = 0.5f * sv[3] + cc;
        *reinterpret_cast<float4*>(&s2b[idx]) = o;
      }
    }
  }
}

// ============ LSE over K ============
__global__ __launch_bounds__(64) void mfa_lse(const float* __restrict__ s2b,
                                              const float* __restrict__ r12a,
                                              const float* __restrict__ r12b,
                                              float* __restrict__ out) {
  int n = blockIdx.x * 64 + threadIdx.x;
  float m = -3.0e38f, s = 0.f;
#pragma unroll 8
  for (int k = 0; k < KC; ++k) {
    size_t idx = (size_t)k * NN + n;
    float t = s2b[idx] + r12a[idx] + r12b[idx];
    float nm = fmaxf(m, t);
    s = s * expf(m - nm) + expf(t - nm);
    m = nm;
  }
  out[n] = m + logf(s);
}

extern "C" void kernel_launch(void* const* d_in, const int* in_sizes, int n_in,
                              void* d_out, int out_size, void* d_ws, size_t ws_size,
                              hipStream_t stream) {
  const float* x  = (const float*)d_in[0];
  const float* MU = (const float*)d_in[1];
  const float* A  = (const float*)d_in[2];
  const float* Dp = (const float*)d_in[3];
  const float* PI = (const float*)d_in[4];
  float* out = (float*)d_out;

  char* base = (char*)d_ws;
  size_t off = 0;
  auto alloc = [&](size_t bytes) -> void* {
    void* p = base + off;
    off += (bytes + 255) & ~(size_t)255;
    return p;
  };
  unsigned short* xaug = (unsigned short*)alloc((size_t)NN * 1024 * 2);    // 16 MB
  unsigned short* As   = (unsigned short*)alloc((size_t)KC * DF * LF * 2); // 8 MB
  unsigned short* Ast  = (unsigned short*)alloc((size_t)KC * LF * DF * 2); // 8 MB
  unsigned short* Waug = (unsigned short*)alloc((size_t)KC * 1024 * 2);    // 256 KB
  unsigned short* Gt   = (unsigned short*)alloc((size_t)KC * LF * DF * 2); // 8 MB
  float* hws           = (float*)alloc((size_t)KC * 64 * 4);
  float* c0g           = (float*)alloc((size_t)KC * 4);
  float* r12a          = (float*)alloc((size_t)KC * NN * 4);               // 2 MB
  float* r12b          = (float*)alloc((size_t)KC * NN * 4);               // 2 MB
  float* s2b           = (float*)alloc((size_t)KC * NN * 4);               // 2 MB

  mfa_prep<<<3072, 256, 0, stream>>>(x, A, Dp, xaug, As, Ast);
  mfa_percomp<<<KC, 256, 0, stream>>>(MU, Dp, PI, Ast, As, Waug, Gt, hws, c0g);
  mfa_main<<<dim3(72, NN / 128), 256, 0, stream>>>(xaug, Gt, Waug, hws, c0g, r12a, r12b, s2b);
  mfa_lse<<<NN / 64, 64, 0, stream>>>(s2b, r12a, r12b, out);
}

// Round 12
// 162.193 us; speedup vs baseline: 1.1493x; 1.0843x over previous
//
#include <hip/hip_runtime.h>
#include <math.h>

// MFA Woodbury log-likelihood:
//   per_comp[k,n] = c0_k + x.w_k - 0.5*x^2.iD_k + 0.5*||G_k^T x - h_k||^2
//   out[n] = logsumexp_k per_comp[k,n]
// As = sqrt(iD).*A (bf16); L = As^T As + I; rank-4 blocked Gauss elimination on
// S=[L|I] -> [U | L_unit^{-1}]; Winv = diag(rsqrt(diag U)) Xu; Gt fused (MFMA).
// main: M=256 tiles, 512 thr (8 waves: 4 m-subtiles x 2 n-subtiles) — 25% less
// staging per FLOP, half the barriers per MFMA vs M=128. Grid (72,16), 72 ≡ 0
// mod 8 -> comp-tile→XCD map row-stable. bx<64 comp; bx-64==(2by+h)&7 heavy
// r12 K-half h; rest exit. All blocks equal duration.
// 4 dispatches: prep, percomp, main, lse.

#define KC 128
#define DF 512
#define LF 64
#define NN 4096

typedef __attribute__((ext_vector_type(8))) short short8;
typedef __attribute__((ext_vector_type(4))) float f32x4;

static __device__ __forceinline__ unsigned short bfr(float f) {
  union { float f; unsigned u; } v; v.f = f;
  return (unsigned short)((v.u + 0x7FFFu + ((v.u >> 16) & 1u)) >> 16);
}
static __device__ __forceinline__ float b2f(unsigned short u) {
  union { unsigned u; float f; } v; v.u = ((unsigned)u) << 16; return v.f;
}
static __device__ __forceinline__ void ldst16(void* lds, const void* g) {
  __builtin_amdgcn_global_load_lds((const __attribute__((address_space(1))) void*)g,
                                   (__attribute__((address_space(3))) void*)lds,
                                   16, 0, 0);
}

// ============ PREP: x -> xaug=[x|x^2] bf16 ; A -> As (d-major) + Ast (i-major) ============
__global__ __launch_bounds__(256) void mfa_prep(const float* __restrict__ x,
                                                const float* __restrict__ A,
                                                const float* __restrict__ Dp,
                                                unsigned short* __restrict__ xaug,
                                                unsigned short* __restrict__ As,
                                                unsigned short* __restrict__ Ast) {
  int b = blockIdx.x, tid = threadIdx.x;
  if (b < 1024) {
    int k = b >> 3, dc = b & 7;
    __shared__ float siDs[64];
    __shared__ unsigned short Tr[64][72];
    if (tid < 64) siDs[tid] = 1.0f / Dp[k * DF + dc * 64 + tid];
    __syncthreads();
#pragma unroll
    for (int q = 0; q < 4; ++q) {
      int f = q * 256 + tid;
      int dd = f >> 4, i4 = (f & 15) * 4;
      float4 v = *reinterpret_cast<const float4*>(&A[((size_t)(k * DF + dc * 64 + dd)) * LF + i4]);
      float s = siDs[dd];
      ushort4 u;
      u.x = bfr(v.x * s); u.y = bfr(v.y * s); u.z = bfr(v.z * s); u.w = bfr(v.w * s);
      *reinterpret_cast<ushort4*>(&As[((size_t)(k * DF + dc * 64 + dd)) * LF + i4]) = u;
      *reinterpret_cast<ushort4*>(&Tr[dd][i4]) = u;
    }
    __syncthreads();
    int i = tid >> 2, ds0 = (tid & 3) * 16;
    unsigned short t16[16];
#pragma unroll
    for (int e = 0; e < 16; ++e) t16[e] = Tr[ds0 + e][i];
    uint4 v0, v1;
    v0.x = (unsigned)t16[0] | ((unsigned)t16[1] << 16);
    v0.y = (unsigned)t16[2] | ((unsigned)t16[3] << 16);
    v0.z = (unsigned)t16[4] | ((unsigned)t16[5] << 16);
    v0.w = (unsigned)t16[6] | ((unsigned)t16[7] << 16);
    v1.x = (unsigned)t16[8] | ((unsigned)t16[9] << 16);
    v1.y = (unsigned)t16[10] | ((unsigned)t16[11] << 16);
    v1.z = (unsigned)t16[12] | ((unsigned)t16[13] << 16);
    v1.w = (unsigned)t16[14] | ((unsigned)t16[15] << 16);
    size_t ro = ((size_t)(k * LF + i)) * DF + dc * 64 + ds0;
    *reinterpret_cast<uint4*>(&Ast[ro]) = v0;
    *reinterpret_cast<uint4*>(&Ast[ro + 8]) = v1;
  } else {
    int f = (b - 1024) * 256 + tid;      // float4 index over NN*DF/4
    float4 v = reinterpret_cast<const float4*>(x)[f];
    int n = f >> 7, c4 = (f & 127) << 2;
    ushort4 a, s;
    a.x = bfr(v.x); a.y = bfr(v.y); a.z = bfr(v.z); a.w = bfr(v.w);
    s.x = bfr(v.x * v.x); s.y = bfr(v.y * v.y); s.z = bfr(v.z * v.z); s.w = bfr(v.w * v.w);
    *reinterpret_cast<ushort4*>(&xaug[(size_t)n * 1024 + c4]) = a;
    *reinterpret_cast<ushort4*>(&xaug[(size_t)n * 1024 + 512 + c4]) = s;
  }
}

// ============ PERCOMP: per k — stats, batched-prefetch syrk+m2, rank-4 elim, h, c0, Gt ============
__global__ __launch_bounds__(256) void mfa_percomp(const float* __restrict__ MU,
                                                   const float* __restrict__ Dp,
                                                   const float* __restrict__ PI,
                                                   const unsigned short* __restrict__ Ast,
                                                   const unsigned short* __restrict__ As,
                                                   unsigned short* __restrict__ Waug,
                                                   unsigned short* __restrict__ Gt,
                                                   float* __restrict__ hws,
                                                   float* __restrict__ c0g) {
  int k = blockIdx.x, tid = threadIdx.x, lane = tid & 63, w = tid >> 6;
  __shared__ float S[64 * 132];            // [L|Xu] stride 132; syrk Tile + gt bufs alias this
  __shared__ unsigned short Wbs[64 * 64];
  __shared__ float smuS[DF];
  __shared__ float m2part[256];
  __shared__ float m2S[64];
  __shared__ float invd_s[64];
  __shared__ float redq[80];
  __shared__ float c0a_s;
  unsigned short* Tile = reinterpret_cast<unsigned short*>(S);  // 32 KB (4 kt-tiles)

  // ---- phase B: stats, smu, Waug ----
  {
    float slog = 0.f, smu2 = 0.f;
#pragma unroll
    for (int p = 0; p < 2; ++p) {
      int d = p * 256 + tid;
      float Dv = Dp[k * DF + d];
      float id = 1.f / (Dv * Dv);
      float mu = MU[k * DF + d];
      float wv = id * mu;
      smuS[d] = mu / Dv;
      Waug[(size_t)k * 1024 + d] = bfr(wv);
      Waug[(size_t)k * 1024 + 512 + d] = bfr(-0.5f * id);
      slog += logf(id);
      smu2 += wv * mu;
    }
#pragma unroll
    for (int m = 1; m < 64; m <<= 1) {
      slog += __shfl_xor(slog, m, 64);
      smu2 += __shfl_xor(smu2, m, 64);
    }
    if (lane == 0) { redq[w] = slog; redq[8 + w] = smu2; }
  }
  __syncthreads();
  if (tid == 0) {
    float sl = 0.f, sm = 0.f;
    for (int q = 0; q < 4; ++q) { sl += redq[q]; sm += redq[8 + q]; }
    c0a_s = PI[k] - 0.5f * (DF * 1.8378770664093453f + sm - sl);
  }

  // ---- phase A: L = Ast Ast^T (MFMA, batched 4-tile prefetch) + fused m2 ----
  f32x4 accL[4];
  f32x4 zero = {0.f, 0.f, 0.f, 0.f};
#pragma unroll
  for (int nj = 0; nj < 4; ++nj) accL[nj] = zero;
  int lr = lane >> 3, lc = lane & 7;
  int gcs = (lc ^ lr) * 8;
  float m2acc = 0.f;
  int mi_i = tid & 63, mi_g = tid >> 6;
  for (int half = 0; half < 2; ++half) {
    __syncthreads();   // previous round's reads done before restaging
#pragma unroll
    for (int kt2 = 0; kt2 < 4; ++kt2) {
      int kt = half * 4 + kt2;
#pragma unroll
      for (int it = 0; it < 2; ++it) {
        int row = w * 8 + it * 32 + lr;
        ldst16(&Tile[(kt2 * 64 + w * 8 + it * 32) * 64],
               Ast + ((size_t)(k * LF + row)) * DF + kt * 64 + gcs);
      }
    }
    __syncthreads();
#pragma unroll
    for (int kt2 = 0; kt2 < 4; ++kt2) {
#pragma unroll
      for (int kk = 0; kk < 2; ++kk) {
        int sw = ((kk * 4 + (lane >> 4)) ^ (lane & 7)) * 8;
        short8 av = *reinterpret_cast<const short8*>(&Tile[(kt2 * 64 + w * 16 + (lane & 15)) * 64 + sw]);
#pragma unroll
        for (int nj = 0; nj < 4; ++nj) {
          short8 bv = *reinterpret_cast<const short8*>(&Tile[(kt2 * 64 + nj * 16 + (lane & 15)) * 64 + sw]);
          accL[nj] = __builtin_amdgcn_mfma_f32_16x16x32_bf16(av, bv, accL[nj], 0, 0, 0);
        }
      }
#pragma unroll
      for (int c2 = 0; c2 < 2; ++c2) {
        int g = mi_g * 2 + c2;
        int slot = g ^ (mi_i & 7);
        const unsigned* cp = reinterpret_cast<const unsigned*>(&Tile[(kt2 * 64 + mi_i) * 64 + slot * 8]);
#pragma unroll
        for (int u2 = 0; u2 < 4; ++u2) {
          unsigned uu = cp[u2];
          int d0 = (half * 4 + kt2) * 64 + g * 8 + u2 * 2;
          m2acc += b2f((unsigned short)(uu & 0xFFFF)) * smuS[d0];
          m2acc += b2f((unsigned short)(uu >> 16)) * smuS[d0 + 1];
        }
      }
    }
  }
  __syncthreads();   // all Tile reads done; S (aliasing Tile) may be written
  // ---- init Xu = I and write L (+I) into S ----
  for (int idx = tid; idx < 4096; idx += 256) {
    int r = idx >> 6, c = idx & 63;
    S[r * 132 + 64 + c] = (r == c) ? 1.f : 0.f;
  }
#pragma unroll
  for (int nj = 0; nj < 4; ++nj)
#pragma unroll
    for (int reg = 0; reg < 4; ++reg) {
      int m = w * 16 + (lane >> 4) * 4 + reg;
      int n = nj * 16 + (lane & 15);
      S[m * 132 + n] = accL[nj][reg] + (m == n ? 1.f : 0.f);
    }
  m2part[tid] = m2acc;
  __syncthreads();
  if (tid < 64) m2S[tid] = m2part[tid] + m2part[tid + 64] + m2part[tid + 128] + m2part[tid + 192];

  // ---- phase D: rank-4 blocked Gauss elimination on S=[L|I] ----
  {
    int rg = tid >> 4, cg = tid & 15;
    for (int Jo = 0; Jo < 16; ++Jo) {
      int J = Jo * 4;
      __syncthreads();
      f32x4 B0 = *reinterpret_cast<f32x4*>(&S[(J + 0) * 132 + J]);
      f32x4 B1 = *reinterpret_cast<f32x4*>(&S[(J + 1) * 132 + J]);
      f32x4 B2 = *reinterpret_cast<f32x4*>(&S[(J + 2) * 132 + J]);
      f32x4 B3 = *reinterpret_cast<f32x4*>(&S[(J + 3) * 132 + J]);
      int cc = J + 4 + cg * 4;
      f32x4 S0 = *reinterpret_cast<f32x4*>(&S[(J + 0) * 132 + cc]);
      f32x4 S1 = *reinterpret_cast<f32x4*>(&S[(J + 1) * 132 + cc]);
      f32x4 S2 = *reinterpret_cast<f32x4*>(&S[(J + 2) * 132 + cc]);
      f32x4 S3 = *reinterpret_cast<f32x4*>(&S[(J + 3) * 132 + cc]);
      f32x4 V[4], TGT[4];
#pragma unroll
      for (int a = 0; a < 4; ++a) {
        int r = J + rg + 16 * a;
        if (r < 64) {
          V[a] = *reinterpret_cast<f32x4*>(&S[r * 132 + J]);
          TGT[a] = *reinterpret_cast<f32x4*>(&S[r * 132 + cc]);
        }
      }
      __syncthreads();
      float p0 = 1.0f / B0[0];
      float m10 = B1[0] * p0;  B1 -= m10 * B0;
      float m20 = B2[0] * p0;  B2 -= m20 * B0;
      float m30 = B3[0] * p0;  B3 -= m30 * B0;
      float p1 = 1.0f / B1[1];
      float m21 = B2[1] * p1;  B2 -= m21 * B1;
      float m31 = B3[1] * p1;  B3 -= m31 * B1;
      float p2 = 1.0f / B2[2];
      float m32 = B3[2] * p2;  B3 -= m32 * B2;
      float p3 = 1.0f / B3[3];
      float T1_0 = -m10;
      float T2_1 = -m21, T2_0 = -m20 - m21 * T1_0;
      float T3_2 = -m32, T3_1 = -m31 - m32 * T2_1, T3_0 = -m30 - m31 * T1_0 - m32 * T2_0;
      if (cg == 0 && rg < 4) {
        f32x4 bw = (rg == 0) ? B0 : (rg == 1) ? B1 : (rg == 2) ? B2 : B3;
        *reinterpret_cast<f32x4*>(&S[(J + rg) * 132 + J]) = bw;
      }
#pragma unroll
      for (int a = 0; a < 4; ++a) {
        int r = J + rg + 16 * a;
        if (r < 64) {
          f32x4 v = V[a];
          float n0 = v[0] * p0;
          float t1 = v[1] - n0 * B0[1];
          float n1 = t1 * p1;
          float t2 = v[2] - n0 * B0[2] - n1 * B1[2];
          float n2 = t2 * p2;
          float t3 = v[3] - n0 * B0[3] - n1 * B1[3] - n2 * B2[3];
          float n3 = t3 * p3;
          int pi = r - J;
          if (pi < 1) n0 = 0.f;
          if (pi < 2) n1 = 0.f;
          if (pi < 3) n2 = 0.f;
          if (pi < 4) n3 = 0.f;
          float cA = n0 + n1 * T1_0 + n2 * T2_0 + n3 * T3_0;
          float cB = n1 + n2 * T2_1 + n3 * T3_1;
          float cC = n2 + n3 * T3_2;
          float cD = n3;
          f32x4 res = TGT[a] - cA * S0 - cB * S1 - cC * S2 - cD * S3;
          *reinterpret_cast<f32x4*>(&S[r * 132 + cc]) = res;
        }
      }
    }
  }
  __syncthreads();
  // ---- diag, logdet, invd ----
  if (tid < 64) {
    float dg2 = S[tid * 132 + tid];
    invd_s[tid] = rsqrtf(dg2);
    redq[tid] = logf(dg2);
  }
  __syncthreads();
  if (tid == 0) {
    float s = 0.f;
    for (int q = 0; q < 64; ++q) s += redq[q];
    c0g[k] = c0a_s - 0.5f * s;
  }
  // ---- h = diag(invd) * (Xu m2) ----
  if (tid < 64) {
    float hsum = 0.f;
#pragma unroll
    for (int j2 = 0; j2 < 64; ++j2) hsum += S[tid * 132 + 64 + j2] * m2S[j2];
    hws[k * 64 + tid] = hsum * invd_s[tid];
  }
  // ---- phase H: build Wbs (bf16, swizzled chunk layout) from Xu ----
  {
    int l = tid >> 2;
#pragma unroll
    for (int q = 0; q < 2; ++q) {
      int sc = (tid & 3) * 2 + q;
      int gch = sc ^ (l & 7);
      float il = invd_s[l];
      unsigned short t8[8];
#pragma unroll
      for (int e = 0; e < 8; ++e) t8[e] = bfr(il * S[l * 132 + 64 + gch * 8 + e]);
      uint4 val;
      val.x = (unsigned)t8[0] | ((unsigned)t8[1] << 16);
      val.y = (unsigned)t8[2] | ((unsigned)t8[3] << 16);
      val.z = (unsigned)t8[4] | ((unsigned)t8[5] << 16);
      val.w = (unsigned)t8[6] | ((unsigned)t8[7] << 16);
      *reinterpret_cast<uint4*>(&Wbs[l * 64 + sc * 8]) = val;
    }
  }
  __syncthreads();   // S dead below: aliased by DsA/CoutA
  // ---- phase I: Gt = siD .* (Wb @ As^T), 4 d-quarters, MFMA ----
  unsigned short* DsA = reinterpret_cast<unsigned short*>(S);          // 128*64 ush
  unsigned short* CoutA = reinterpret_cast<unsigned short*>(S) + 8192; // 64*132 ush
  f32x4 zero2 = {0.f, 0.f, 0.f, 0.f};
  for (int dq = 0; dq < 4; ++dq) {
#pragma unroll
    for (int it = 0; it < 4; ++it) {
      int row = w * 8 + it * 32 + lr;
      ldst16(&DsA[(w * 8 + it * 32) * 64], As + ((size_t)(k * DF + dq * 128 + row)) * LF + gcs);
    }
    __syncthreads();
    f32x4 gacc[4][2];
#pragma unroll
    for (int mi = 0; mi < 4; ++mi)
#pragma unroll
      for (int nj = 0; nj < 2; ++nj) gacc[mi][nj] = zero2;
#pragma unroll
    for (int kk = 0; kk < 2; ++kk) {
      int sw = ((kk * 4 + (lane >> 4)) ^ (lane & 7)) * 8;
      short8 av[4], bv[2];
#pragma unroll
      for (int mi = 0; mi < 4; ++mi)
        av[mi] = *reinterpret_cast<const short8*>(&Wbs[(mi * 16 + (lane & 15)) * 64 + sw]);
#pragma unroll
      for (int nj = 0; nj < 2; ++nj)
        bv[nj] = *reinterpret_cast<const short8*>(&DsA[(w * 32 + nj * 16 + (lane & 15)) * 64 + sw]);
#pragma unroll
      for (int mi = 0; mi < 4; ++mi)
#pragma unroll
        for (int nj = 0; nj < 2; ++nj)
          gacc[mi][nj] = __builtin_amdgcn_mfma_f32_16x16x32_bf16(av[mi], bv[nj], gacc[mi][nj], 0, 0, 0);
    }
    float siD[2];
#pragma unroll
    for (int nj = 0; nj < 2; ++nj)
      siD[nj] = 1.0f / Dp[k * DF + dq * 128 + w * 32 + nj * 16 + (lane & 15)];
#pragma unroll
    for (int mi = 0; mi < 4; ++mi)
#pragma unroll
      for (int nj = 0; nj < 2; ++nj) {
        int dl = w * 32 + nj * 16 + (lane & 15);
#pragma unroll
        for (int reg = 0; reg < 4; ++reg) {
          int l = mi * 16 + (lane >> 4) * 4 + reg;
          CoutA[l * 132 + dl] = bfr(gacc[mi][nj][reg] * siD[nj]);
        }
      }
    __syncthreads();
    {
      int l = tid >> 2, seg = (tid & 3) * 32;
      uint4* dst = reinterpret_cast<uint4*>(&Gt[((size_t)(k * LF + l)) * DF + dq * 128 + seg]);
#pragma unroll
      for (int u = 0; u < 4; ++u) {
        unsigned short t8[8];
#pragma unroll
        for (int e = 0; e < 8; ++e) t8[e] = CoutA[l * 132 + seg + u * 8 + e];
        uint4 val;
        val.x = (unsigned)t8[0] | ((unsigned)t8[1] << 16);
        val.y = (unsigned)t8[2] | ((unsigned)t8[3] << 16);
        val.z = (unsigned)t8[4] | ((unsigned)t8[5] << 16);
        val.w = (unsigned)t8[6] | ((unsigned)t8[7] << 16);
        dst[u] = val;
      }
    }
    __syncthreads();
  }
}

// ============ MAIN: M=256 tiles, 512 thr. grid (72,16); bx<64 comp tile;
//              bx-64==(2by+h)&7 heavy r12 K-half h; else exit. ============
__global__ __launch_bounds__(512) void mfa_main(const unsigned short* __restrict__ xaug,
                                                const unsigned short* __restrict__ Gt,
                                                const unsigned short* __restrict__ Waug,
                                                const float* __restrict__ hws,
                                                const float* __restrict__ c0g,
                                                float* __restrict__ r12a,
                                                float* __restrict__ r12b,
                                                float* __restrict__ s2b) {
  int bx = blockIdx.x, by = blockIdx.y;
  bool heavy = false;
  int half = 0;
  if (bx >= 64) {
    int slot = bx - 64;
    if (slot == ((2 * by) & 7)) { heavy = true; half = 0; }
    else if (slot == ((2 * by + 1) & 7)) { heavy = true; half = 1; }
    else return;                        // filler (keeps grid.x % 8 == 0)
  }
  int tid = threadIdx.x, lane = tid & 63, w = tid >> 6;
  int wy = w & 3, wx = w >> 2;          // 4 m-subtiles x 2 n-subtiles
  __shared__ unsigned short As[256 * 64];   // 32 KB
  __shared__ unsigned short Bs[128 * 64];   // 16 KB
  f32x4 acc[4][4];
  f32x4 zero = {0.f, 0.f, 0.f, 0.f};
#pragma unroll
  for (int mi = 0; mi < 4; ++mi)
#pragma unroll
    for (int nj = 0; nj < 4; ++nj) acc[mi][nj] = zero;
  int nbase = by * 256;
  const unsigned short* xg = xaug + (size_t)nbase * 1024;
  const unsigned short* gg;
  size_t bstride;
  int kt0;
  if (heavy) { gg = Waug; bstride = 1024; kt0 = half * 8; }
  else       { gg = Gt + (size_t)(bx * 128) * DF; bstride = DF; kt0 = 0; }
  int lr = lane >> 3, lc = lane & 7;
  int gcs = (lc ^ lr) * 8;
  for (int kti = 0; kti < 8; ++kti) {
    int kt = kt0 + kti;
#pragma unroll
    for (int it = 0; it < 4; ++it) {
      int row = w * 8 + it * 64 + lr;
      ldst16(&As[(w * 8 + it * 64) * 64], xg + (size_t)row * 1024 + kt * 64 + gcs);
    }
#pragma unroll
    for (int it = 0; it < 2; ++it) {
      int row = w * 8 + it * 64 + lr;
      ldst16(&Bs[(w * 8 + it * 64) * 64], gg + (size_t)row * bstride + kt * 64 + gcs);
    }
    __syncthreads();
#pragma unroll
    for (int kk = 0; kk < 2; ++kk) {
      int sw = ((kk * 4 + (lane >> 4)) ^ (lane & 7)) * 8;
      short8 av[4], bv[4];
#pragma unroll
      for (int mi = 0; mi < 4; ++mi)
        av[mi] = *reinterpret_cast<const short8*>(&As[(wy * 64 + mi * 16 + (lane & 15)) * 64 + sw]);
#pragma unroll
      for (int nj = 0; nj < 4; ++nj)
        bv[nj] = *reinterpret_cast<const short8*>(&Bs[(wx * 64 + nj * 16 + (lane & 15)) * 64 + sw]);
#pragma unroll
      for (int mi = 0; mi < 4; ++mi)
#pragma unroll
        for (int nj = 0; nj < 4; ++nj)
          acc[mi][nj] = __builtin_amdgcn_mfma_f32_16x16x32_bf16(av[mi], bv[nj], acc[mi][nj], 0, 0, 0);
    }
    __syncthreads();
  }
  if (heavy) {
    float* rout = half ? r12b : r12a;
#pragma unroll
    for (int mi = 0; mi < 4; ++mi)
#pragma unroll
      for (int nj = 0; nj < 4; ++nj) {
        int ccol = wx * 64 + nj * 16 + (lane & 15);
        int nrow = nbase + wy * 64 + mi * 16 + (lane >> 4) * 4;
        float4 o;
        o.x = acc[mi][nj][0]; o.y = acc[mi][nj][1]; o.z = acc[mi][nj][2]; o.w = acc[mi][nj][3];
        *reinterpret_cast<float4*>(&rout[(size_t)ccol * NN + nrow]) = o;
      }
  } else {
    int comp = bx * 2 + wx;
    float hv[4];
#pragma unroll
    for (int nj = 0; nj < 4; ++nj) hv[nj] = hws[comp * 64 + nj * 16 + (lane & 15)];
    float cc = c0g[comp];
    int rbase = nbase + wy * 64;
#pragma unroll
    for (int mi = 0; mi < 4; ++mi) {
      f32x4 sv;
#pragma unroll
      for (int reg = 0; reg < 4; ++reg) {
        float s = 0.f;
#pragma unroll
        for (int nj = 0; nj < 4; ++nj) {
          float dlt = acc[mi][nj][reg] - hv[nj];
          s += dlt * dlt;
        }
        s += __shfl_xor(s, 1, 64);
        s += __shfl_xor(s, 2, 64);
        s += __shfl_xor(s, 4, 64);
        s += __shfl_xor(s, 8, 64);
        sv[reg] = s;
      }
      if ((lane & 15) == 0) {
        int nr = rbase + mi * 16 + (lane >> 4) * 4;
        size_t idx = (size_t)comp * NN + nr;
        float4 o;
        o.x = 0.5f * sv[0] + cc;
        o.y = 0.5f * sv[1] + cc;
        o.z = 0.5f * sv[2] + cc;
        o.w = 0.5f * sv[3] + cc;
        *reinterpret_cast<float4*>(&s2b[idx]) = o;
      }
    }
  }
}

// ============ LSE over K ============
__global__ __launch_bounds__(64) void mfa_lse(const float* __restrict__ s2b,
                                              const float* __restrict__ r12a,
                                              const float* __restrict__ r12b,
                                              float* __restrict__ out) {
  int n = blockIdx.x * 64 + threadIdx.x;
  float m = -3.0e38f, s = 0.f;
#pragma unroll 8
  for (int k = 0; k < KC; ++k) {
    size_t idx = (size_t)k * NN + n;
    float t = s2b[idx] + r12a[idx] + r12b[idx];
    float nm = fmaxf(m, t);
    s = s * expf(m - nm) + expf(t - nm);
    m = nm;
  }
  out[n] = m + logf(s);
}

extern "C" void kernel_launch(void* const* d_in, const int* in_sizes, int n_in,
                              void* d_out, int out_size, void* d_ws, size_t ws_size,
                              hipStream_t stream) {
  const float* x  = (const float*)d_in[0];
  const float* MU = (const float*)d_in[1];
  const float* A  = (const float*)d_in[2];
  const float* Dp = (const float*)d_in[3];
  const float* PI = (const float*)d_in[4];
  float* out = (float*)d_out;

  char* base = (char*)d_ws;
  size_t off = 0;
  auto alloc = [&](size_t bytes) -> void* {
    void* p = base + off;
    off += (bytes + 255) & ~(size_t)255;
    return p;
  };
  unsigned short* xaug = (unsigned short*)alloc((size_t)NN * 1024 * 2);    // 16 MB
  unsigned short* As   = (unsigned short*)alloc((size_t)KC * DF * LF * 2); // 8 MB
  unsigned short* Ast  = (unsigned short*)alloc((size_t)KC * LF * DF * 2); // 8 MB
  unsigned short* Waug = (unsigned short*)alloc((size_t)KC * 1024 * 2);    // 256 KB
  unsigned short* Gt   = (unsigned short*)alloc((size_t)KC * LF * DF * 2); // 8 MB
  float* hws           = (float*)alloc((size_t)KC * 64 * 4);
  float* c0g           = (float*)alloc((size_t)KC * 4);
  float* r12a          = (float*)alloc((size_t)KC * NN * 4);               // 2 MB
  float* r12b          = (float*)alloc((size_t)KC * NN * 4);               // 2 MB
  float* s2b           = (float*)alloc((size_t)KC * NN * 4);               // 2 MB

  mfa_prep<<<3072, 256, 0, stream>>>(x, A, Dp, xaug, As, Ast);
  mfa_percomp<<<KC, 256, 0, stream>>>(MU, Dp, PI, Ast, As, Waug, Gt, hws, c0g);
  mfa_main<<<dim3(72, NN / 256), 512, 0, stream>>>(xaug, Gt, Waug, hws, c0g, r12a, r12b, s2b);
  mfa_lse<<<NN / 64, 64, 0, stream>>>(s2b, r12a, r12b, out);
}